// Round 1
// baseline (5539.087 us; speedup 1.0000x reference)
//
#include <hip/hip_runtime.h>
#include <math.h>

#define NU 60001
#define NI 40001
#define NN 100002   // NU + NI
#define EG 1000000
#define EB 500000
#define BATCH 4096

// ---------- helpers ----------
__device__ inline float wave_sum(float v) {
#pragma unroll
  for (int off = 32; off > 0; off >>= 1) v += __shfl_down(v, off);
  return __shfl(v, 0);
}

// ---------- init / copy ----------
__global__ void k_init_concat(const float4* __restrict__ ue, const float4* __restrict__ ie,
                              float4* __restrict__ out) {
  long i = (long)blockIdx.x * blockDim.x + threadIdx.x;  // over NN*16 float4s
  if (i >= (long)NN * 16) return;
  out[i] = (i < (long)NU * 16) ? ue[i] : ie[i - (long)NU * 16];
}

__global__ void k_copy(const float4* __restrict__ in, float4* __restrict__ out, long n4) {
  long i = (long)blockIdx.x * blockDim.x + threadIdx.x;
  if (i < n4) out[i] = in[i];
}

// ---------- degree / dinv ----------
__global__ void k_deg(const int* __restrict__ dst, int E, float* __restrict__ deg) {
  int e = blockIdx.x * blockDim.x + threadIdx.x;
  if (e < E) atomicAdd(deg + dst[e], 1.0f);
}

__global__ void k_dinv(float* __restrict__ deg, int n) {
  int i = blockIdx.x * blockDim.x + threadIdx.x;
  if (i < n) {
    float d = deg[i];
    deg[i] = (d > 0.f) ? (1.0f / sqrtf(d)) : 0.f;
  }
}

// ---------- matmul: out = A(N x 64) @ W(64 x 64) ----------
__global__ void k_matmul(const float* __restrict__ A, const float* __restrict__ W,
                         float* __restrict__ out, int N) {
  __shared__ float Ws[64][64];
  int t = threadIdx.x;
  for (int i = t; i < 4096; i += 256) Ws[i >> 6][i & 63] = W[i];
  __syncthreads();
  int row = blockIdx.x * 4 + (t >> 6);
  int d = t & 63;
  if (row >= N) return;
  const float* a = A + (long)row * 64;
  float s = 0.f;
#pragma unroll
  for (int k = 0; k < 64; k++) s = fmaf(a[k], Ws[k][d], s);
  out[(long)row * 64 + d] = s;
}

__global__ void k_matmul_concat(const float* __restrict__ ue, const float* __restrict__ ie,
                                const float* __restrict__ W, float* __restrict__ out, int N) {
  __shared__ float Ws[64][64];
  int t = threadIdx.x;
  for (int i = t; i < 4096; i += 256) Ws[i >> 6][i & 63] = W[i];
  __syncthreads();
  int row = blockIdx.x * 4 + (t >> 6);
  int d = t & 63;
  if (row >= N) return;
  const float* a = (row < NU) ? (ue + (long)row * 64) : (ie + (long)(row - NU) * 64);
  float s = 0.f;
#pragma unroll
  for (int k = 0; k < 64; k++) s = fmaf(a[k], Ws[k][d], s);
  out[(long)row * 64 + d] = s;
}

// ---------- scatter: agg[dst] += hw[src] * dinv[src]*dinv[dst] ----------
__global__ void k_scatter(const float* __restrict__ hw, const int* __restrict__ src,
                          const int* __restrict__ dst, const float* __restrict__ dinv,
                          float* __restrict__ agg, int E) {
  int tid = blockIdx.x * blockDim.x + threadIdx.x;
  int e = tid >> 4;    // 16 threads per edge
  int part = tid & 15;
  if (e >= E) return;
  int s = src[e], d = dst[e];
  float c = dinv[s] * dinv[d];
  if (c == 0.f) return;
  float4 v = *(const float4*)(hw + (long)s * 64 + part * 4);
  float* o = agg + (long)d * 64 + part * 4;
  atomicAdd(o + 0, v.x * c);
  atomicAdd(o + 1, v.y * c);
  atomicAdd(o + 2, v.z * c);
  atomicAdd(o + 3, v.w * c);
}

// ---------- normalize (agg + b), write h back to agg, res += h*scale ----------
__global__ void k_norm_acc(float* __restrict__ agg, const float* __restrict__ bias,
                           float* __restrict__ res, float scale, int N) {
  int t = threadIdx.x;
  int row = blockIdx.x * 4 + (t >> 6);
  int d = t & 63;
  if (row >= N) return;
  long idx = (long)row * 64 + d;
  float v = agg[idx] + bias[d];
  float ss = wave_sum(v * v);
  float nrm = fmaxf(sqrtf(ss), 1e-12f);
  float h = v / nrm;
  agg[idx] = h;
  res[idx] += h * scale;
}

// ---------- fused attention + BPR loss ----------
__device__ inline void item_iw(const float* __restrict__ G, const float* __restrict__ B0,
                               const float* __restrict__ B1, const float* __restrict__ B2,
                               int item, int lane, float iw[3]) {
  long o = ((long)(NU + item)) * 64 + lane;
  float g = G[o], t0 = B0[o], t1 = B1[o], t2 = B2[o];
  float g00 = wave_sum(t0 * t0), g01 = wave_sum(t0 * t1), g02 = wave_sum(t0 * t2);
  float g11 = wave_sum(t1 * t1), g12 = wave_sum(t1 * t2), g22 = wave_sum(t2 * t2);
  const float S = 0.125f;
  float gm[3][3] = {{g00, g01, g02}, {g01, g11, g12}, {g02, g12, g22}};
#pragma unroll
  for (int j = 0; j < 3; j++) {
    float a0 = gm[j][0] * S, a1 = gm[j][1] * S, a2 = gm[j][2] * S;
    float m = fmaxf(a0, fmaxf(a1, a2));
    float e0 = expf(a0 - m), e1 = expf(a1 - m), e2 = expf(a2 - m);
    float inv = 1.f / (e0 + e1 + e2);
    float att = (e0 * t0 + e1 * t1 + e2 * t2) * inv;
    iw[j] = g + 0.55f * att;
  }
}

__global__ void k_loss(const float* __restrict__ G, const float* __restrict__ B0,
                       const float* __restrict__ B1, const float* __restrict__ B2,
                       const int* __restrict__ batch, float* __restrict__ acc) {
  int tid = blockIdx.x * blockDim.x + threadIdx.x;
  int wid = tid >> 6, lane = tid & 63;
  if (wid >= BATCH * 3) return;
  int i = wid % 3, k = wid / 3;
  const int* bd = batch + ((long)k * 3 + i) * 3;
  int u = bd[0], p = bd[1], q = bd[2];

  // user row (uw[u, i])
  float uf;
  {
    long o = (long)u * 64 + lane;
    float g = G[o], t0 = B0[o], t1 = B1[o], t2 = B2[o];
    float g00 = wave_sum(t0 * t0), g01 = wave_sum(t0 * t1), g02 = wave_sum(t0 * t2);
    float g11 = wave_sum(t1 * t1), g12 = wave_sum(t1 * t2), g22 = wave_sum(t2 * t2);
    const float S = 0.125f;
    float a0, a1, a2;
    if (i == 0) { a0 = g00; a1 = g01; a2 = g02; }
    else if (i == 1) { a0 = g01; a1 = g11; a2 = g12; }
    else { a0 = g02; a1 = g12; a2 = g22; }
    a0 *= S; a1 *= S; a2 *= S;
    float m = fmaxf(a0, fmaxf(a1, a2));
    float e0 = expf(a0 - m), e1 = expf(a1 - m), e2 = expf(a2 - m);
    float inv = 1.f / (e0 + e1 + e2);
    float att = (e0 * t0 + e1 * t1 + e2 * t2) * inv;
    uf = 2.35f * g + 0.242f * att;
  }

  float iwp[3], iwq[3];
  item_iw(G, B0, B1, B2, p, lane, iwp);
  item_iw(G, B0, B1, B2, q, lane, iwq);

  float loc = 0.f;
#pragma unroll
  for (int j = 0; j < 3; j++) {
    float sp = wave_sum(uf * iwp[j]);
    float sq = wave_sum(uf * iwq[j]);
    float x = sp - sq;
    loc += fminf(x, 0.f) - log1pf(expf(-fabsf(x)));  // log_sigmoid(x), stable
  }
  if (lane == 0) atomicAdd(acc, loc);
}

// ---------- Frobenius sum-of-squares ----------
__global__ void k_sumsq(const float* __restrict__ x, long n, float* __restrict__ acc) {
  long stride = (long)gridDim.x * blockDim.x;
  float v = 0.f;
  for (long i = (long)blockIdx.x * blockDim.x + threadIdx.x; i < n; i += stride) {
    float t = x[i];
    v = fmaf(t, t, v);
  }
  v = wave_sum(v);
  if ((threadIdx.x & 63) == 0) atomicAdd(acc, v);
}

__global__ void k_final(const float* __restrict__ acc, float* __restrict__ out) {
  out[0] = -acc[0] * (1.0f / (float)BATCH) +
           0.001f * ((sqrtf(acc[1]) + sqrtf(acc[2])) / (float)NI);
}

// ---------- launch ----------
extern "C" void kernel_launch(void* const* d_in, const int* in_sizes, int n_in,
                              void* d_out, int out_size, void* d_ws, size_t ws_size,
                              hipStream_t stream) {
  const float* ue = (const float*)d_in[0];   // (60001, 64)
  const float* ie = (const float*)d_in[1];   // (40001, 64)
  const float* gW = (const float*)d_in[2];   // (2, 64, 64)
  const float* gb = (const float*)d_in[3];   // (2, 64)
  const float* bW = (const float*)d_in[4];   // (3, 2, 64, 64)
  const float* bb = (const float*)d_in[5];   // (3, 2, 64)
  const int* eg = (const int*)d_in[6];       // (2, 1e6)
  const int* eb = (const int*)d_in[7];       // (3, 2, 5e5)
  const int* batch = (const int*)d_in[8];    // (4096, 3, 3)
  float* out = (float*)d_out;

  float* ws = (float*)d_ws;
  const long NE = (long)NN * 64;
  float* G = ws;
  float* B0 = G + NE;
  float* B1 = G + 2 * NE;
  float* B2 = G + 3 * NE;
  float* Bs[3] = {B0, B1, B2};
  float* HW = G + 4 * NE;
  float* AGG = G + 5 * NE;
  float* DINV = G + 6 * NE;       // NN floats (deg then dinv, in place)
  float* ACC = DINV + NN;         // [0]=loss sum, [1]=ssq user, [2]=ssq item

  hipMemsetAsync(ACC, 0, 3 * sizeof(float), stream);

  const long n4 = (long)NN * 16;
  const int CP_B = (int)((n4 + 255) / 256);
  const int MM_B = (NN + 3) / 4;

  auto encode = [&](const int* src, const int* dst, int E, const float* W, const float* b,
                    const float* input /* null -> concat(ue,ie) */, float* RES) {
    hipMemsetAsync(DINV, 0, NN * sizeof(float), stream);
    k_deg<<<(E + 255) / 256, 256, 0, stream>>>(dst, E, DINV);
    k_dinv<<<(NN + 255) / 256, 256, 0, stream>>>(DINV, NN);
    for (int l = 0; l < 2; l++) {
      if (l == 0 && input == nullptr)
        k_matmul_concat<<<MM_B, 256, 0, stream>>>(ue, ie, W, HW, NN);
      else
        k_matmul<<<MM_B, 256, 0, stream>>>((l == 0) ? input : AGG, W + l * 4096, HW, NN);
      hipMemsetAsync(AGG, 0, NE * sizeof(float), stream);
      int sb = (int)(((long)E * 16 + 255) / 256);
      k_scatter<<<sb, 256, 0, stream>>>(HW, src, dst, DINV, AGG, E);
      k_norm_acc<<<MM_B, 256, 0, stream>>>(AGG, b + l * 64, RES, 1.0f / (float)(l + 1), NN);
    }
  };

  // global encoder: res init = concat(ue, ie)
  k_init_concat<<<CP_B, 256, 0, stream>>>((const float4*)ue, (const float4*)ie, (float4*)G);
  encode(eg, eg + EG, EG, gW, gb, nullptr, G);

  // behavior encoders: input = G, res init = copy of G
  for (int bi = 0; bi < 3; bi++) {
    k_copy<<<CP_B, 256, 0, stream>>>((const float4*)G, (float4*)Bs[bi], n4);
    encode(eb + (long)bi * 2 * EB, eb + (long)bi * 2 * EB + EB, EB,
           bW + (long)bi * 2 * 4096, bb + (long)bi * 128, G, Bs[bi]);
  }

  // fused attention + BPR loss
  k_loss<<<(BATCH * 3 * 64) / 256, 256, 0, stream>>>(G, B0, B1, B2, batch, ACC);

  // regularization norms
  k_sumsq<<<512, 256, 0, stream>>>(ue, (long)NU * 64, ACC + 1);
  k_sumsq<<<512, 256, 0, stream>>>(ie, (long)NI * 64, ACC + 2);

  k_final<<<1, 1, 0, stream>>>(ACC, out);
}

// Round 2
// 1884.306 us; speedup vs baseline: 2.9396x; 2.9396x over previous
//
#include <hip/hip_runtime.h>
#include <math.h>

#define NU 60001
#define NI 40001
#define NN 100002   // NU + NI
#define EG 1000000
#define EB 500000
#define BATCH 4096

// ---------- helpers ----------
__device__ inline float wave_sum(float v) {
#pragma unroll
  for (int off = 32; off > 0; off >>= 1) v += __shfl_down(v, off);
  return __shfl(v, 0);
}

// ---------- init / copy ----------
__global__ void k_init_concat(const float4* __restrict__ ue, const float4* __restrict__ ie,
                              float4* __restrict__ out) {
  long i = (long)blockIdx.x * blockDim.x + threadIdx.x;  // over NN*16 float4s
  if (i >= (long)NN * 16) return;
  out[i] = (i < (long)NU * 16) ? ue[i] : ie[i - (long)NU * 16];
}

__global__ void k_copy(const float4* __restrict__ in, float4* __restrict__ out, long n4) {
  long i = (long)blockIdx.x * blockDim.x + threadIdx.x;
  if (i < n4) out[i] = in[i];
}

// ---------- CSR build ----------
__global__ void k_deg_i(const int* __restrict__ dst, int E, int* __restrict__ cnt) {
  int e = blockIdx.x * blockDim.x + threadIdx.x;
  if (e < E) atomicAdd(cnt + dst[e], 1);
}

__global__ void k_dinv(const int* __restrict__ cnt, float* __restrict__ dinv, int n) {
  int i = blockIdx.x * blockDim.x + threadIdx.x;
  if (i < n) {
    int d = cnt[i];
    dinv[i] = (d > 0) ? rsqrtf((float)d) : 0.f;
  }
}

// exclusive scan of cnt[NN] -> offs[NN]; 512 elems per block
__global__ void k_scanA(const int* __restrict__ cnt, int* __restrict__ offs,
                        int* __restrict__ part) {
  __shared__ int sd[256];
  int t = threadIdx.x;
  int base = blockIdx.x * 512;
  int i0 = base + 2 * t, i1 = i0 + 1;
  int a = (i0 < NN) ? cnt[i0] : 0;
  int b = (i1 < NN) ? cnt[i1] : 0;
  sd[t] = a + b;
  __syncthreads();
  for (int off = 1; off < 256; off <<= 1) {
    int v = (t >= off) ? sd[t - off] : 0;
    __syncthreads();
    sd[t] += v;
    __syncthreads();
  }
  int excl = (t > 0) ? sd[t - 1] : 0;
  if (i0 < NN) offs[i0] = excl;
  if (i1 < NN) offs[i1] = excl + a;
  if (t == 255) part[blockIdx.x] = sd[255];
}

__global__ void k_scanB(int* __restrict__ part, int nb) {
  __shared__ int sd[256];
  int t = threadIdx.x;
  sd[t] = (t < nb) ? part[t] : 0;
  __syncthreads();
  for (int off = 1; off < 256; off <<= 1) {
    int v = (t >= off) ? sd[t - off] : 0;
    __syncthreads();
    sd[t] += v;
    __syncthreads();
  }
  part[t] = (t > 0) ? sd[t - 1] : 0;
}

__global__ void k_scanC(int* __restrict__ offs, const int* __restrict__ part,
                        int* __restrict__ curs) {
  int i = blockIdx.x * blockDim.x + threadIdx.x;
  if (i < NN) {
    int v = offs[i] + part[i >> 9];
    offs[i] = v;
    curs[i] = v;
  }
}

__global__ void k_bucket(const int* __restrict__ src, const int* __restrict__ dst,
                         const float* __restrict__ dinv, int E, int* __restrict__ curs,
                         int* __restrict__ srcs, float* __restrict__ coef) {
  int e = blockIdx.x * blockDim.x + threadIdx.x;
  if (e >= E) return;
  int s = src[e], d = dst[e];
  int pos = atomicAdd(curs + d, 1);
  srcs[pos] = s;
  coef[pos] = dinv[s] * dinv[d];
}

// ---------- matmul: out = A(N x 64) @ W(64 x 64) ----------
__global__ void k_matmul(const float* __restrict__ A, const float* __restrict__ W,
                         float* __restrict__ out, int N) {
  __shared__ float Ws[64][64];
  int t = threadIdx.x;
  for (int i = t; i < 4096; i += 256) Ws[i >> 6][i & 63] = W[i];
  __syncthreads();
  int row = blockIdx.x * 4 + (t >> 6);
  int d = t & 63;
  if (row >= N) return;
  const float* a = A + (long)row * 64;
  float s = 0.f;
#pragma unroll
  for (int k = 0; k < 64; k++) s = fmaf(a[k], Ws[k][d], s);
  out[(long)row * 64 + d] = s;
}

__global__ void k_matmul_concat(const float* __restrict__ ue, const float* __restrict__ ie,
                                const float* __restrict__ W, float* __restrict__ out, int N) {
  __shared__ float Ws[64][64];
  int t = threadIdx.x;
  for (int i = t; i < 4096; i += 256) Ws[i >> 6][i & 63] = W[i];
  __syncthreads();
  int row = blockIdx.x * 4 + (t >> 6);
  int d = t & 63;
  if (row >= N) return;
  const float* a = (row < NU) ? (ue + (long)row * 64) : (ie + (long)(row - NU) * 64);
  float s = 0.f;
#pragma unroll
  for (int k = 0; k < 64; k++) s = fmaf(a[k], Ws[k][d], s);
  out[(long)row * 64 + d] = s;
}

// ---------- gather + bias + normalize + residual, fused ----------
// one wave per dst node; lane = dim
__global__ void __launch_bounds__(256) k_gather_norm(
    const float* __restrict__ hw, const int* __restrict__ srcs,
    const float* __restrict__ coef, const int* __restrict__ offs,
    const int* __restrict__ cnt, const float* __restrict__ bias,
    float* __restrict__ agg, float* __restrict__ res, float scale) {
  int t = threadIdx.x;
  int node = blockIdx.x * 4 + (t >> 6);
  int lane = t & 63;
  if (node >= NN) return;
  int st = offs[node], n = cnt[node];
  float acc = 0.f;
  for (int k = 0; k < n; k++) {
    int s = srcs[st + k];
    float c = coef[st + k];
    acc = fmaf(hw[(long)s * 64 + lane], c, acc);
  }
  float v = acc + bias[lane];
  float ss = wave_sum(v * v);
  float nrm = fmaxf(sqrtf(ss), 1e-12f);
  float h = v / nrm;
  long idx = (long)node * 64 + lane;
  agg[idx] = h;
  res[idx] += h * scale;
}

// ---------- fused attention + BPR loss ----------
__device__ inline void item_iw(const float* __restrict__ G, const float* __restrict__ B0,
                               const float* __restrict__ B1, const float* __restrict__ B2,
                               int item, int lane, float iw[3]) {
  long o = ((long)(NU + item)) * 64 + lane;
  float g = G[o], t0 = B0[o], t1 = B1[o], t2 = B2[o];
  float g00 = wave_sum(t0 * t0), g01 = wave_sum(t0 * t1), g02 = wave_sum(t0 * t2);
  float g11 = wave_sum(t1 * t1), g12 = wave_sum(t1 * t2), g22 = wave_sum(t2 * t2);
  const float S = 0.125f;
  float gm[3][3] = {{g00, g01, g02}, {g01, g11, g12}, {g02, g12, g22}};
#pragma unroll
  for (int j = 0; j < 3; j++) {
    float a0 = gm[j][0] * S, a1 = gm[j][1] * S, a2 = gm[j][2] * S;
    float m = fmaxf(a0, fmaxf(a1, a2));
    float e0 = expf(a0 - m), e1 = expf(a1 - m), e2 = expf(a2 - m);
    float inv = 1.f / (e0 + e1 + e2);
    float att = (e0 * t0 + e1 * t1 + e2 * t2) * inv;
    iw[j] = g + 0.55f * att;
  }
}

__global__ void k_loss(const float* __restrict__ G, const float* __restrict__ B0,
                       const float* __restrict__ B1, const float* __restrict__ B2,
                       const int* __restrict__ batch, float* __restrict__ acc) {
  int tid = blockIdx.x * blockDim.x + threadIdx.x;
  int wid = tid >> 6, lane = tid & 63;
  if (wid >= BATCH * 3) return;
  int i = wid % 3, k = wid / 3;
  const int* bd = batch + ((long)k * 3 + i) * 3;
  int u = bd[0], p = bd[1], q = bd[2];

  float uf;
  {
    long o = (long)u * 64 + lane;
    float g = G[o], t0 = B0[o], t1 = B1[o], t2 = B2[o];
    float g00 = wave_sum(t0 * t0), g01 = wave_sum(t0 * t1), g02 = wave_sum(t0 * t2);
    float g11 = wave_sum(t1 * t1), g12 = wave_sum(t1 * t2), g22 = wave_sum(t2 * t2);
    const float S = 0.125f;
    float a0, a1, a2;
    if (i == 0) { a0 = g00; a1 = g01; a2 = g02; }
    else if (i == 1) { a0 = g01; a1 = g11; a2 = g12; }
    else { a0 = g02; a1 = g12; a2 = g22; }
    a0 *= S; a1 *= S; a2 *= S;
    float m = fmaxf(a0, fmaxf(a1, a2));
    float e0 = expf(a0 - m), e1 = expf(a1 - m), e2 = expf(a2 - m);
    float inv = 1.f / (e0 + e1 + e2);
    float att = (e0 * t0 + e1 * t1 + e2 * t2) * inv;
    uf = 2.35f * g + 0.242f * att;
  }

  float iwp[3], iwq[3];
  item_iw(G, B0, B1, B2, p, lane, iwp);
  item_iw(G, B0, B1, B2, q, lane, iwq);

  float loc = 0.f;
#pragma unroll
  for (int j = 0; j < 3; j++) {
    float sp = wave_sum(uf * iwp[j]);
    float sq = wave_sum(uf * iwq[j]);
    float x = sp - sq;
    loc += fminf(x, 0.f) - log1pf(expf(-fabsf(x)));  // stable log_sigmoid
  }
  if (lane == 0) atomicAdd(acc, loc);
}

// ---------- Frobenius sum-of-squares ----------
__global__ void k_sumsq(const float* __restrict__ x, long n, float* __restrict__ acc) {
  long stride = (long)gridDim.x * blockDim.x;
  float v = 0.f;
  for (long i = (long)blockIdx.x * blockDim.x + threadIdx.x; i < n; i += stride) {
    float t = x[i];
    v = fmaf(t, t, v);
  }
  v = wave_sum(v);
  if ((threadIdx.x & 63) == 0) atomicAdd(acc, v);
}

__global__ void k_final(const float* __restrict__ acc, float* __restrict__ out) {
  out[0] = -acc[0] * (1.0f / (float)BATCH) +
           0.001f * ((sqrtf(acc[1]) + sqrtf(acc[2])) / (float)NI);
}

// ---------- launch ----------
extern "C" void kernel_launch(void* const* d_in, const int* in_sizes, int n_in,
                              void* d_out, int out_size, void* d_ws, size_t ws_size,
                              hipStream_t stream) {
  const float* ue = (const float*)d_in[0];   // (60001, 64)
  const float* ie = (const float*)d_in[1];   // (40001, 64)
  const float* gW = (const float*)d_in[2];   // (2, 64, 64)
  const float* gb = (const float*)d_in[3];   // (2, 64)
  const float* bW = (const float*)d_in[4];   // (3, 2, 64, 64)
  const float* bb = (const float*)d_in[5];   // (3, 2, 64)
  const int* eg = (const int*)d_in[6];       // (2, 1e6)
  const int* eb = (const int*)d_in[7];       // (3, 2, 5e5)
  const int* batch = (const int*)d_in[8];    // (4096, 3, 3)
  float* out = (float*)d_out;

  float* ws = (float*)d_ws;
  const long NE = (long)NN * 64;
  float* G = ws;
  float* B0 = G + NE;
  float* B1 = G + 2 * NE;
  float* B2 = G + 3 * NE;
  float* Bs[3] = {B0, B1, B2};
  float* HW = G + 4 * NE;
  float* AGG = G + 5 * NE;
  float* DINV = G + 6 * NE;             // NN floats
  float* ACC = DINV + NN;               // 3 floats
  int* CNT = (int*)(ACC + 8);           // NN ints
  int* OFFS = CNT + NN;                 // NN ints
  int* CURS = OFFS + NN;                // NN ints
  int* PART = CURS + NN;                // 512 ints
  int* SRCS = PART + 512;               // up to EG ints
  float* COEF = (float*)(SRCS + EG);    // up to EG floats

  hipMemsetAsync(ACC, 0, 3 * sizeof(float), stream);

  const long n4 = (long)NN * 16;
  const int CP_B = (int)((n4 + 255) / 256);
  const int MM_B = (NN + 3) / 4;
  const int NB_SCAN = (NN + 511) / 512;  // 196

  auto encode = [&](const int* src, const int* dst, int E, const float* W, const float* b,
                    const float* input /* null -> concat(ue,ie) */, float* RES) {
    // --- CSR build (once per edge set, reused by both layers) ---
    hipMemsetAsync(CNT, 0, NN * sizeof(int), stream);
    k_deg_i<<<(E + 255) / 256, 256, 0, stream>>>(dst, E, CNT);
    k_dinv<<<(NN + 255) / 256, 256, 0, stream>>>(CNT, DINV, NN);
    k_scanA<<<NB_SCAN, 256, 0, stream>>>(CNT, OFFS, PART);
    k_scanB<<<1, 256, 0, stream>>>(PART, NB_SCAN);
    k_scanC<<<(NN + 255) / 256, 256, 0, stream>>>(OFFS, PART, CURS);
    k_bucket<<<(E + 255) / 256, 256, 0, stream>>>(src, dst, DINV, E, CURS, SRCS, COEF);
    // --- two GCN layers ---
    for (int l = 0; l < 2; l++) {
      if (l == 0 && input == nullptr)
        k_matmul_concat<<<MM_B, 256, 0, stream>>>(ue, ie, W, HW, NN);
      else
        k_matmul<<<MM_B, 256, 0, stream>>>((l == 0) ? input : AGG, W + l * 4096, HW, NN);
      k_gather_norm<<<MM_B, 256, 0, stream>>>(HW, SRCS, COEF, OFFS, CNT, b + l * 64,
                                              AGG, RES, 1.0f / (float)(l + 1));
    }
  };

  // global encoder: res init = concat(ue, ie)
  k_init_concat<<<CP_B, 256, 0, stream>>>((const float4*)ue, (const float4*)ie, (float4*)G);
  encode(eg, eg + EG, EG, gW, gb, nullptr, G);

  // behavior encoders: input = G, res init = copy of G
  for (int bi = 0; bi < 3; bi++) {
    k_copy<<<CP_B, 256, 0, stream>>>((const float4*)G, (float4*)Bs[bi], n4);
    encode(eb + (long)bi * 2 * EB, eb + (long)bi * 2 * EB + EB, EB,
           bW + (long)bi * 2 * 4096, bb + (long)bi * 128, G, Bs[bi]);
  }

  // fused attention + BPR loss
  k_loss<<<(BATCH * 3 * 64) / 256, 256, 0, stream>>>(G, B0, B1, B2, batch, ACC);

  // regularization norms
  k_sumsq<<<512, 256, 0, stream>>>(ue, (long)NU * 64, ACC + 1);
  k_sumsq<<<512, 256, 0, stream>>>(ie, (long)NI * 64, ACC + 2);

  k_final<<<1, 1, 0, stream>>>(ACC, out);
}

// Round 3
// 1523.115 us; speedup vs baseline: 3.6367x; 1.2371x over previous
//
#include <hip/hip_runtime.h>
#include <math.h>

#define NU 60001
#define NI 40001
#define NN 100002   // NU + NI
#define EG 1000000
#define EB 500000
#define BATCH 4096

// ---------- helpers ----------
__device__ inline float wave_sum(float v) {
#pragma unroll
  for (int off = 32; off > 0; off >>= 1) v += __shfl_down(v, off);
  return __shfl(v, 0);
}

__device__ inline float sub_sum16(float v) {  // reduce within 16-lane subgroup
#pragma unroll
  for (int off = 8; off > 0; off >>= 1) v += __shfl_xor(v, off);
  return v;
}

__device__ inline float dot4(float4 a, float4 b) {
  return fmaf(a.x, b.x, fmaf(a.y, b.y, fmaf(a.z, b.z, a.w * b.w)));
}

// ---------- CSR build ----------
__global__ void k_deg_i(const int* __restrict__ dst, int E, int* __restrict__ cnt) {
  int e = blockIdx.x * blockDim.x + threadIdx.x;
  if (e < E) atomicAdd(cnt + dst[e], 1);
}

// exclusive scan of cnt[NN] -> offs[NN]; 512 elems per block
__global__ void k_scanA(const int* __restrict__ cnt, int* __restrict__ offs,
                        int* __restrict__ part) {
  __shared__ int sd[256];
  int t = threadIdx.x;
  int base = blockIdx.x * 512;
  int i0 = base + 2 * t, i1 = i0 + 1;
  int a = (i0 < NN) ? cnt[i0] : 0;
  int b = (i1 < NN) ? cnt[i1] : 0;
  sd[t] = a + b;
  __syncthreads();
  for (int off = 1; off < 256; off <<= 1) {
    int v = (t >= off) ? sd[t - off] : 0;
    __syncthreads();
    sd[t] += v;
    __syncthreads();
  }
  int excl = (t > 0) ? sd[t - 1] : 0;
  if (i0 < NN) offs[i0] = excl;
  if (i1 < NN) offs[i1] = excl + a;
  if (t == 255) part[blockIdx.x] = sd[255];
}

__global__ void k_scanB(int* __restrict__ part, int nb) {
  __shared__ int sd[256];
  int t = threadIdx.x;
  sd[t] = (t < nb) ? part[t] : 0;
  __syncthreads();
  for (int off = 1; off < 256; off <<= 1) {
    int v = (t >= off) ? sd[t - off] : 0;
    __syncthreads();
    sd[t] += v;
    __syncthreads();
  }
  part[t] = (t > 0) ? sd[t - 1] : 0;
}

// finalize offs, init cursor, compute dinv (fused)
__global__ void k_scanC(int* __restrict__ offs, const int* __restrict__ part,
                        int* __restrict__ curs, const int* __restrict__ cnt,
                        float* __restrict__ dinv) {
  int i = blockIdx.x * blockDim.x + threadIdx.x;
  if (i < NN) {
    int v = offs[i] + part[i >> 9];
    offs[i] = v;
    curs[i] = v;
    int c = cnt[i];
    dinv[i] = (c > 0) ? rsqrtf((float)c) : 0.f;
  }
}

__global__ void k_bucket(const int* __restrict__ src, const int* __restrict__ dst,
                         const float* __restrict__ dinv, int E, int* __restrict__ curs,
                         int2* __restrict__ edges) {
  int e = blockIdx.x * blockDim.x + threadIdx.x;
  if (e >= E) return;
  int s = src[e], d = dst[e];
  int pos = atomicAdd(curs + d, 1);
  edges[pos] = make_int2(s, __float_as_int(dinv[s] * dinv[d]));
}

// ---------- fused GCN layer: gather(h) -> @W -> +b -> l2norm -> res ----------
// one wave per node; lane = dim
// RESMODE 0: res[idx] = in_row(node) + h      (layer 1; scale implicit 1)
// RESMODE 1: res[idx] += h * scale            (layer 2)
template <bool CONCAT, int RESMODE>
__global__ void __launch_bounds__(256) k_gcn_layer(
    const float* __restrict__ in, const float* __restrict__ in2,
    const int2* __restrict__ edges, const int* __restrict__ offs,
    const int* __restrict__ cnt, const float* __restrict__ W,
    const float* __restrict__ bias, float* __restrict__ aggout,
    float* __restrict__ res, float scale) {
  __shared__ float Ws[64][64];
  int t = threadIdx.x;
  for (int i = t; i < 4096; i += 256) Ws[i >> 6][i & 63] = W[i];
  __syncthreads();
  int node = blockIdx.x * 4 + (t >> 6);
  int lane = t & 63;
  if (node >= NN) return;
  int st = offs[node], n = cnt[node];
  float acc = 0.f;
  for (int base = 0; base < n; base += 64) {
    int m = min(64, n - base);
    int2 e = (lane < m) ? edges[st + base + lane] : make_int2(0, 0);
    int k = 0;
    for (; k + 3 < m; k += 4) {
      int s0 = __shfl(e.x, k), s1 = __shfl(e.x, k + 1);
      int s2 = __shfl(e.x, k + 2), s3 = __shfl(e.x, k + 3);
      float c0 = __int_as_float(__shfl(e.y, k));
      float c1 = __int_as_float(__shfl(e.y, k + 1));
      float c2 = __int_as_float(__shfl(e.y, k + 2));
      float c3 = __int_as_float(__shfl(e.y, k + 3));
      const float *r0, *r1, *r2, *r3;
      if (CONCAT) {
        r0 = (s0 < NU) ? in + (long)s0 * 64 : in2 + (long)(s0 - NU) * 64;
        r1 = (s1 < NU) ? in + (long)s1 * 64 : in2 + (long)(s1 - NU) * 64;
        r2 = (s2 < NU) ? in + (long)s2 * 64 : in2 + (long)(s2 - NU) * 64;
        r3 = (s3 < NU) ? in + (long)s3 * 64 : in2 + (long)(s3 - NU) * 64;
      } else {
        r0 = in + (long)s0 * 64; r1 = in + (long)s1 * 64;
        r2 = in + (long)s2 * 64; r3 = in + (long)s3 * 64;
      }
      float x0 = r0[lane], x1 = r1[lane], x2 = r2[lane], x3 = r3[lane];
      acc = fmaf(x0, c0, acc);
      acc = fmaf(x1, c1, acc);
      acc = fmaf(x2, c2, acc);
      acc = fmaf(x3, c3, acc);
    }
    for (; k < m; k++) {
      int s = __shfl(e.x, k);
      float c = __int_as_float(__shfl(e.y, k));
      const float* r;
      if (CONCAT) r = (s < NU) ? in + (long)s * 64 : in2 + (long)(s - NU) * 64;
      else r = in + (long)s * 64;
      acc = fmaf(r[lane], c, acc);
    }
  }
  // matvec: v[d] = sum_k acc_k * W[k][d] + bias[d]
  float v0 = bias[lane], v1 = 0.f;
#pragma unroll
  for (int k = 0; k < 64; k += 2) {
    v0 = fmaf(__shfl(acc, k), Ws[k][lane], v0);
    v1 = fmaf(__shfl(acc, k + 1), Ws[k + 1][lane], v1);
  }
  float v = v0 + v1;
  float ss = wave_sum(v * v);
  float h = v / fmaxf(sqrtf(ss), 1e-12f);
  long idx = (long)node * 64 + lane;
  aggout[idx] = h;
  if (RESMODE == 0) {
    float b0;
    if (CONCAT) b0 = (node < NU) ? in[idx] : in2[(long)(node - NU) * 64 + lane];
    else b0 = in[idx];
    res[idx] = b0 + h;
  } else {
    res[idx] += h * scale;
  }
}

// ---------- fused attention + BPR loss (16-lane subgroups, float4/lane) ----------
__device__ inline void item_iw4(const float* __restrict__ G, const float* __restrict__ B0,
                                const float* __restrict__ B1, const float* __restrict__ B2,
                                long o, float4& iw0, float4& iw1, float4& iw2) {
  float4 g = *(const float4*)(G + o);
  float4 t0 = *(const float4*)(B0 + o);
  float4 t1 = *(const float4*)(B1 + o);
  float4 t2 = *(const float4*)(B2 + o);
  float g00 = sub_sum16(dot4(t0, t0)), g01 = sub_sum16(dot4(t0, t1));
  float g02 = sub_sum16(dot4(t0, t2)), g11 = sub_sum16(dot4(t1, t1));
  float g12 = sub_sum16(dot4(t1, t2)), g22 = sub_sum16(dot4(t2, t2));
  const float S = 0.125f;
  float gm[3][3] = {{g00, g01, g02}, {g01, g11, g12}, {g02, g12, g22}};
  float4* out[3] = {&iw0, &iw1, &iw2};
#pragma unroll
  for (int j = 0; j < 3; j++) {
    float a0 = gm[j][0] * S, a1 = gm[j][1] * S, a2 = gm[j][2] * S;
    float m = fmaxf(a0, fmaxf(a1, a2));
    float e0 = expf(a0 - m), e1 = expf(a1 - m), e2 = expf(a2 - m);
    float inv = 1.f / (e0 + e1 + e2);
    float w0 = e0 * inv, w1 = e1 * inv, w2 = e2 * inv;
    float4 r;
    r.x = fmaf(0.55f, w0 * t0.x + w1 * t1.x + w2 * t2.x, g.x);
    r.y = fmaf(0.55f, w0 * t0.y + w1 * t1.y + w2 * t2.y, g.y);
    r.z = fmaf(0.55f, w0 * t0.z + w1 * t1.z + w2 * t2.z, g.z);
    r.w = fmaf(0.55f, w0 * t0.w + w1 * t1.w + w2 * t2.w, g.w);
    *out[j] = r;
  }
}

__global__ void __launch_bounds__(256) k_loss(
    const float* __restrict__ G, const float* __restrict__ B0,
    const float* __restrict__ B1, const float* __restrict__ B2,
    const int* __restrict__ batch, float* __restrict__ acc) {
  int tid = blockIdx.x * blockDim.x + threadIdx.x;
  int lane = tid & 63;
  int sub = lane >> 4, sl = lane & 15;
  int task = (tid >> 6) * 4 + sub;  // task = k*3 + i
  if (task >= BATCH * 3) return;
  int i = task % 3;
  const int* bd = batch + (long)task * 3;
  int u = bd[0], p = bd[1], q = bd[2];

  // user feature uf (float4 slice)
  float4 uf;
  {
    long o = (long)u * 64 + sl * 4;
    float4 g = *(const float4*)(G + o);
    float4 t0 = *(const float4*)(B0 + o);
    float4 t1 = *(const float4*)(B1 + o);
    float4 t2 = *(const float4*)(B2 + o);
    float4 ti = (i == 0) ? t0 : ((i == 1) ? t1 : t2);
    float a0 = sub_sum16(dot4(ti, t0)) * 0.125f;
    float a1 = sub_sum16(dot4(ti, t1)) * 0.125f;
    float a2 = sub_sum16(dot4(ti, t2)) * 0.125f;
    float m = fmaxf(a0, fmaxf(a1, a2));
    float e0 = expf(a0 - m), e1 = expf(a1 - m), e2 = expf(a2 - m);
    float inv = 1.f / (e0 + e1 + e2);
    float w0 = e0 * inv, w1 = e1 * inv, w2 = e2 * inv;
    uf.x = fmaf(2.35f, g.x, 0.242f * (w0 * t0.x + w1 * t1.x + w2 * t2.x));
    uf.y = fmaf(2.35f, g.y, 0.242f * (w0 * t0.y + w1 * t1.y + w2 * t2.y));
    uf.z = fmaf(2.35f, g.z, 0.242f * (w0 * t0.z + w1 * t1.z + w2 * t2.z));
    uf.w = fmaf(2.35f, g.w, 0.242f * (w0 * t0.w + w1 * t1.w + w2 * t2.w));
  }

  float4 p0, p1, p2, q0, q1, q2;
  item_iw4(G, B0, B1, B2, ((long)(NU + p)) * 64 + sl * 4, p0, p1, p2);
  item_iw4(G, B0, B1, B2, ((long)(NU + q)) * 64 + sl * 4, q0, q1, q2);

  float sp0 = sub_sum16(dot4(uf, p0)), sq0 = sub_sum16(dot4(uf, q0));
  float sp1 = sub_sum16(dot4(uf, p1)), sq1 = sub_sum16(dot4(uf, q1));
  float sp2 = sub_sum16(dot4(uf, p2)), sq2 = sub_sum16(dot4(uf, q2));

  if (sl == 0) {
    float loc = 0.f;
    float xs[3] = {sp0 - sq0, sp1 - sq1, sp2 - sq2};
#pragma unroll
    for (int j = 0; j < 3; j++) {
      float x = xs[j];
      loc += fminf(x, 0.f) - log1pf(expf(-fabsf(x)));
    }
    atomicAdd(acc, loc);
  }
}

// ---------- Frobenius sum-of-squares ----------
__global__ void k_sumsq(const float* __restrict__ x, long n, float* __restrict__ acc) {
  long stride = (long)gridDim.x * blockDim.x;
  float v = 0.f;
  for (long i = (long)blockIdx.x * blockDim.x + threadIdx.x; i < n; i += stride) {
    float t = x[i];
    v = fmaf(t, t, v);
  }
  v = wave_sum(v);
  if ((threadIdx.x & 63) == 0) atomicAdd(acc, v);
}

__global__ void k_final(const float* __restrict__ acc, float* __restrict__ out) {
  out[0] = -acc[0] * (1.0f / (float)BATCH) +
           0.001f * ((sqrtf(acc[1]) + sqrtf(acc[2])) / (float)NI);
}

// ---------- launch ----------
extern "C" void kernel_launch(void* const* d_in, const int* in_sizes, int n_in,
                              void* d_out, int out_size, void* d_ws, size_t ws_size,
                              hipStream_t stream) {
  const float* ue = (const float*)d_in[0];   // (60001, 64)
  const float* ie = (const float*)d_in[1];   // (40001, 64)
  const float* gW = (const float*)d_in[2];   // (2, 64, 64)
  const float* gb = (const float*)d_in[3];   // (2, 64)
  const float* bW = (const float*)d_in[4];   // (3, 2, 64, 64)
  const float* bb = (const float*)d_in[5];   // (3, 2, 64)
  const int* eg = (const int*)d_in[6];       // (2, 1e6)
  const int* eb = (const int*)d_in[7];       // (3, 2, 5e5)
  const int* batch = (const int*)d_in[8];    // (4096, 3, 3)
  float* out = (float*)d_out;

  float* ws = (float*)d_ws;
  const long NE = (long)NN * 64;
  float* G = ws;
  float* B0 = G + NE;
  float* B1 = G + 2 * NE;
  float* B2 = G + 3 * NE;
  float* Bs[3] = {B0, B1, B2};
  float* AGGA = G + 4 * NE;
  float* AGGB = G + 5 * NE;
  float* DINV = G + 6 * NE;             // NN floats
  float* ACC = DINV + NN;               // 3 floats (+pad)
  int* CNT = (int*)(ACC + 8);           // NN ints
  int* OFFS = CNT + NN;                 // NN ints
  int* CURS = OFFS + NN;                // NN ints
  int* PART = CURS + NN;                // 512 ints
  int2* EDGES = (int2*)(PART + 512);    // EG int2

  hipMemsetAsync(ACC, 0, 3 * sizeof(float), stream);

  const int MM_B = (NN + 3) / 4;
  const int NB_SCAN = (NN + 511) / 512;  // 196

  auto build_csr = [&](const int* src, const int* dst, int E) {
    hipMemsetAsync(CNT, 0, NN * sizeof(int), stream);
    k_deg_i<<<(E + 255) / 256, 256, 0, stream>>>(dst, E, CNT);
    k_scanA<<<NB_SCAN, 256, 0, stream>>>(CNT, OFFS, PART);
    k_scanB<<<1, 256, 0, stream>>>(PART, NB_SCAN);
    k_scanC<<<(NN + 255) / 256, 256, 0, stream>>>(OFFS, PART, CURS, CNT, DINV);
    k_bucket<<<(E + 255) / 256, 256, 0, stream>>>(src, dst, DINV, E, CURS, EDGES);
  };

  // ---- global encoder: input/res-base = concat(ue, ie), res -> G ----
  build_csr(eg, eg + EG, EG);
  k_gcn_layer<true, 0><<<MM_B, 256, 0, stream>>>(ue, ie, EDGES, OFFS, CNT, gW, gb,
                                                 AGGA, G, 1.0f);
  k_gcn_layer<false, 1><<<MM_B, 256, 0, stream>>>(AGGA, nullptr, EDGES, OFFS, CNT,
                                                  gW + 4096, gb + 64, AGGB, G, 0.5f);

  // ---- behavior encoders: input = G, res-base = G, res -> Bs[bi] ----
  for (int bi = 0; bi < 3; bi++) {
    build_csr(eb + (long)bi * 2 * EB, eb + (long)bi * 2 * EB + EB, EB);
    const float* W = bW + (long)bi * 2 * 4096;
    const float* b = bb + (long)bi * 128;
    k_gcn_layer<false, 0><<<MM_B, 256, 0, stream>>>(G, nullptr, EDGES, OFFS, CNT, W, b,
                                                    AGGA, Bs[bi], 1.0f);
    k_gcn_layer<false, 1><<<MM_B, 256, 0, stream>>>(AGGA, nullptr, EDGES, OFFS, CNT,
                                                    W + 4096, b + 64, AGGB, Bs[bi], 0.5f);
  }

  // ---- fused attention + BPR loss ----
  k_loss<<<(BATCH * 3) / 16, 256, 0, stream>>>(G, B0, B1, B2, batch, ACC);

  // ---- regularization norms ----
  k_sumsq<<<512, 256, 0, stream>>>(ue, (long)NU * 64, ACC + 1);
  k_sumsq<<<512, 256, 0, stream>>>(ie, (long)NI * 64, ACC + 2);

  k_final<<<1, 1, 0, stream>>>(ACC, out);
}

// Round 4
// 1219.471 us; speedup vs baseline: 4.5422x; 1.2490x over previous
//
#include <hip/hip_runtime.h>
#include <math.h>

#define NU 60001
#define NI 40001
#define NN 100002   // NU + NI
#define EG 1000000
#define EB 500000
#define BATCH 4096

// ---------- helpers ----------
__device__ inline float wave_sum(float v) {
#pragma unroll
  for (int off = 32; off > 0; off >>= 1) v += __shfl_down(v, off);
  return __shfl(v, 0);
}

__device__ inline float sub_sum16(float v) {  // reduce within 16-lane subgroup
#pragma unroll
  for (int off = 8; off > 0; off >>= 1) v += __shfl_xor(v, off);
  return v;
}

__device__ inline float dot4(float4 a, float4 b) {
  return fmaf(a.x, b.x, fmaf(a.y, b.y, fmaf(a.z, b.z, a.w * b.w)));
}

__device__ inline unsigned short f2b(float f) {  // fp32 -> bf16 RNE
  unsigned u = __float_as_uint(f);
  return (unsigned short)((u + 0x7fffu + ((u >> 16) & 1u)) >> 16);
}
__device__ inline float b2f(unsigned short h) {
  return __uint_as_float((unsigned)h << 16);
}

// ---------- bf16 concat table ----------
__global__ void k_tobf16_concat(const float4* __restrict__ ue, const float4* __restrict__ ie,
                                ushort4* __restrict__ out) {
  long i = (long)blockIdx.x * blockDim.x + threadIdx.x;  // over NN*16 float4s
  if (i >= (long)NN * 16) return;
  float4 v = (i < (long)NU * 16) ? ue[i] : ie[i - (long)NU * 16];
  ushort4 o;
  o.x = f2b(v.x); o.y = f2b(v.y); o.z = f2b(v.z); o.w = f2b(v.w);
  out[i] = o;
}

// ---------- CSR build ----------
__global__ void k_deg_i(const int* __restrict__ dst, int E, int* __restrict__ cnt) {
  int e = blockIdx.x * blockDim.x + threadIdx.x;
  if (e < E) atomicAdd(cnt + dst[e], 1);
}

// exclusive scan of cnt[NN] -> offs[NN]; 512 elems per block
__global__ void k_scanA(const int* __restrict__ cnt, int* __restrict__ offs,
                        int* __restrict__ part) {
  __shared__ int sd[256];
  int t = threadIdx.x;
  int base = blockIdx.x * 512;
  int i0 = base + 2 * t, i1 = i0 + 1;
  int a = (i0 < NN) ? cnt[i0] : 0;
  int b = (i1 < NN) ? cnt[i1] : 0;
  sd[t] = a + b;
  __syncthreads();
  for (int off = 1; off < 256; off <<= 1) {
    int v = (t >= off) ? sd[t - off] : 0;
    __syncthreads();
    sd[t] += v;
    __syncthreads();
  }
  int excl = (t > 0) ? sd[t - 1] : 0;
  if (i0 < NN) offs[i0] = excl;
  if (i1 < NN) offs[i1] = excl + a;
  if (t == 255) part[blockIdx.x] = sd[255];
}

__global__ void k_scanB(int* __restrict__ part, int nb) {
  __shared__ int sd[256];
  int t = threadIdx.x;
  sd[t] = (t < nb) ? part[t] : 0;
  __syncthreads();
  for (int off = 1; off < 256; off <<= 1) {
    int v = (t >= off) ? sd[t - off] : 0;
    __syncthreads();
    sd[t] += v;
    __syncthreads();
  }
  part[t] = (t > 0) ? sd[t - 1] : 0;
}

// finalize offs, init cursor, compute dinv (fused)
__global__ void k_scanC(int* __restrict__ offs, const int* __restrict__ part,
                        int* __restrict__ curs, const int* __restrict__ cnt,
                        float* __restrict__ dinv) {
  int i = blockIdx.x * blockDim.x + threadIdx.x;
  if (i < NN) {
    int v = offs[i] + part[i >> 9];
    offs[i] = v;
    curs[i] = v;
    int c = cnt[i];
    dinv[i] = (c > 0) ? rsqrtf((float)c) : 0.f;
  }
}

// edge payload: x = src byte-offset into bf16 table (src*128), y = coef bits
__global__ void k_bucket(const int* __restrict__ src, const int* __restrict__ dst,
                         const float* __restrict__ dinv, int E, int* __restrict__ curs,
                         int2* __restrict__ edges) {
  int e = blockIdx.x * blockDim.x + threadIdx.x;
  if (e >= E) return;
  int s = src[e], d = dst[e];
  int pos = atomicAdd(curs + d, 1);
  edges[pos] = make_int2(s << 7, __float_as_int(dinv[s] * dinv[d]));
}

// ---------- fused GCN layer core ----------
// Gather: 16-lane subgroups, lane holds 4 dims (bf16 8B load); 4 edges/iter.
// Then acc -> LDS -> 64x64 matvec (lane=dim) -> +bias -> l2norm.
__device__ inline float gcn_core(const ushort* __restrict__ tb, const int2* __restrict__ edges,
                                 int st, int n, const float (*Ws)[64], float* accs_w,
                                 const float* __restrict__ bias, int lane, int sub, int sl) {
  float4 acc = make_float4(0.f, 0.f, 0.f, 0.f);
  for (int bse = 0; bse < n; bse += 64) {
    int m = min(64, n - bse);
    int2 e = (lane < m) ? edges[st + bse + lane] : make_int2(0, 0);
    int iters = (m + 3) >> 2;
    for (int k = 0; k < iters; k++) {
      int j = (k << 2) + sub;
      int off = __shfl(e.x, j);                       // src*128 (0 if padded)
      float c = __int_as_float(__shfl(e.y, j));       // 0 if padded
      ushort4 xr = *(const ushort4*)((const char*)tb + off + (sl << 3));
      acc.x = fmaf(b2f(xr.x), c, acc.x);
      acc.y = fmaf(b2f(xr.y), c, acc.y);
      acc.z = fmaf(b2f(xr.z), c, acc.z);
      acc.w = fmaf(b2f(xr.w), c, acc.w);
    }
  }
  // reduce across the 4 subgroups
  acc.x += __shfl_xor(acc.x, 16); acc.y += __shfl_xor(acc.y, 16);
  acc.z += __shfl_xor(acc.z, 16); acc.w += __shfl_xor(acc.w, 16);
  acc.x += __shfl_xor(acc.x, 32); acc.y += __shfl_xor(acc.y, 32);
  acc.z += __shfl_xor(acc.z, 32); acc.w += __shfl_xor(acc.w, 32);
  if (sub == 0) *(float4*)(accs_w + (sl << 2)) = acc;  // wave-local, no barrier needed
  float v0 = bias[lane], v1 = 0.f;
#pragma unroll
  for (int k4 = 0; k4 < 16; k4++) {
    float4 a4 = *(const float4*)(accs_w + (k4 << 2));
    v0 = fmaf(a4.x, Ws[(k4 << 2) + 0][lane], v0);
    v1 = fmaf(a4.y, Ws[(k4 << 2) + 1][lane], v1);
    v0 = fmaf(a4.z, Ws[(k4 << 2) + 2][lane], v0);
    v1 = fmaf(a4.w, Ws[(k4 << 2) + 3][lane], v1);
  }
  float v = v0 + v1;
  float ss = wave_sum(v * v);
  return v / fmaxf(sqrtf(ss), 1e-12f);
}

// Layer 1: h1 = norm(conv(tb)); write bf16 h1 only.
__global__ void __launch_bounds__(256) k_gcn_l1(
    const ushort* __restrict__ tb, const int2* __restrict__ edges,
    const int* __restrict__ offs, const int* __restrict__ cnt,
    const float* __restrict__ W, const float* __restrict__ bias,
    unsigned short* __restrict__ agg16) {
  __shared__ float Ws[64][64];
  __shared__ float accs[4][64];
  int t = threadIdx.x;
  for (int i = t; i < 4096; i += 256) Ws[i >> 6][i & 63] = W[i];
  __syncthreads();
  int w = t >> 6, lane = t & 63, sub = lane >> 4, sl = lane & 15;
  int node = blockIdx.x * 4 + w;
  if (node >= NN) return;
  float h = gcn_core(tb, edges, offs[node], cnt[node], Ws, accs[w], bias, lane, sub, sl);
  agg16[(long)node * 64 + lane] = f2b(h);
}

// Layer 2: h2 = norm(conv(h1_16)); res = base + h1 + 0.5*h2 (+ optional bf16 shadow).
template <bool BASE_CONCAT, bool WRITE_B16>
__global__ void __launch_bounds__(256) k_gcn_l2(
    const ushort* __restrict__ h1_16, const int2* __restrict__ edges,
    const int* __restrict__ offs, const int* __restrict__ cnt,
    const float* __restrict__ W, const float* __restrict__ bias,
    const float* __restrict__ base, const float* __restrict__ base2,
    float* __restrict__ res, unsigned short* __restrict__ res16) {
  __shared__ float Ws[64][64];
  __shared__ float accs[4][64];
  int t = threadIdx.x;
  for (int i = t; i < 4096; i += 256) Ws[i >> 6][i & 63] = W[i];
  __syncthreads();
  int w = t >> 6, lane = t & 63, sub = lane >> 4, sl = lane & 15;
  int node = blockIdx.x * 4 + w;
  if (node >= NN) return;
  float h = gcn_core(h1_16, edges, offs[node], cnt[node], Ws, accs[w], bias, lane, sub, sl);
  long idx = (long)node * 64 + lane;
  float own = b2f(h1_16[idx]);  // h1 row for this node
  float b0;
  if (BASE_CONCAT) b0 = (node < NU) ? base[idx] : base2[(long)(node - NU) * 64 + lane];
  else b0 = base[idx];
  float r = b0 + own + 0.5f * h;
  res[idx] = r;
  if (WRITE_B16) res16[idx] = f2b(r);
}

// ---------- fused attention + BPR loss (16-lane subgroups, float4/lane) ----------
__device__ inline void item_iw4(const float* __restrict__ G, const float* __restrict__ B0,
                                const float* __restrict__ B1, const float* __restrict__ B2,
                                long o, float4& iw0, float4& iw1, float4& iw2) {
  float4 g = *(const float4*)(G + o);
  float4 t0 = *(const float4*)(B0 + o);
  float4 t1 = *(const float4*)(B1 + o);
  float4 t2 = *(const float4*)(B2 + o);
  float g00 = sub_sum16(dot4(t0, t0)), g01 = sub_sum16(dot4(t0, t1));
  float g02 = sub_sum16(dot4(t0, t2)), g11 = sub_sum16(dot4(t1, t1));
  float g12 = sub_sum16(dot4(t1, t2)), g22 = sub_sum16(dot4(t2, t2));
  const float S = 0.125f;
  float gm[3][3] = {{g00, g01, g02}, {g01, g11, g12}, {g02, g12, g22}};
  float4* out[3] = {&iw0, &iw1, &iw2};
#pragma unroll
  for (int j = 0; j < 3; j++) {
    float a0 = gm[j][0] * S, a1 = gm[j][1] * S, a2 = gm[j][2] * S;
    float m = fmaxf(a0, fmaxf(a1, a2));
    float e0 = expf(a0 - m), e1 = expf(a1 - m), e2 = expf(a2 - m);
    float inv = 1.f / (e0 + e1 + e2);
    float w0 = e0 * inv, w1 = e1 * inv, w2 = e2 * inv;
    float4 r;
    r.x = fmaf(0.55f, w0 * t0.x + w1 * t1.x + w2 * t2.x, g.x);
    r.y = fmaf(0.55f, w0 * t0.y + w1 * t1.y + w2 * t2.y, g.y);
    r.z = fmaf(0.55f, w0 * t0.z + w1 * t1.z + w2 * t2.z, g.z);
    r.w = fmaf(0.55f, w0 * t0.w + w1 * t1.w + w2 * t2.w, g.w);
    *out[j] = r;
  }
}

__global__ void __launch_bounds__(256) k_loss(
    const float* __restrict__ G, const float* __restrict__ B0,
    const float* __restrict__ B1, const float* __restrict__ B2,
    const int* __restrict__ batch, float* __restrict__ acc) {
  int tid = blockIdx.x * blockDim.x + threadIdx.x;
  int lane = tid & 63;
  int sub = lane >> 4, sl = lane & 15;
  int task = (tid >> 6) * 4 + sub;  // task = k*3 + i
  if (task >= BATCH * 3) return;
  int i = task % 3;
  const int* bd = batch + (long)task * 3;
  int u = bd[0], p = bd[1], q = bd[2];

  float4 uf;
  {
    long o = (long)u * 64 + sl * 4;
    float4 g = *(const float4*)(G + o);
    float4 t0 = *(const float4*)(B0 + o);
    float4 t1 = *(const float4*)(B1 + o);
    float4 t2 = *(const float4*)(B2 + o);
    float4 ti = (i == 0) ? t0 : ((i == 1) ? t1 : t2);
    float a0 = sub_sum16(dot4(ti, t0)) * 0.125f;
    float a1 = sub_sum16(dot4(ti, t1)) * 0.125f;
    float a2 = sub_sum16(dot4(ti, t2)) * 0.125f;
    float m = fmaxf(a0, fmaxf(a1, a2));
    float e0 = expf(a0 - m), e1 = expf(a1 - m), e2 = expf(a2 - m);
    float inv = 1.f / (e0 + e1 + e2);
    float w0 = e0 * inv, w1 = e1 * inv, w2 = e2 * inv;
    uf.x = fmaf(2.35f, g.x, 0.242f * (w0 * t0.x + w1 * t1.x + w2 * t2.x));
    uf.y = fmaf(2.35f, g.y, 0.242f * (w0 * t0.y + w1 * t1.y + w2 * t2.y));
    uf.z = fmaf(2.35f, g.z, 0.242f * (w0 * t0.z + w1 * t1.z + w2 * t2.z));
    uf.w = fmaf(2.35f, g.w, 0.242f * (w0 * t0.w + w1 * t1.w + w2 * t2.w));
  }

  float4 p0, p1, p2, q0, q1, q2;
  item_iw4(G, B0, B1, B2, ((long)(NU + p)) * 64 + sl * 4, p0, p1, p2);
  item_iw4(G, B0, B1, B2, ((long)(NU + q)) * 64 + sl * 4, q0, q1, q2);

  float sp0 = sub_sum16(dot4(uf, p0)), sq0 = sub_sum16(dot4(uf, q0));
  float sp1 = sub_sum16(dot4(uf, p1)), sq1 = sub_sum16(dot4(uf, q1));
  float sp2 = sub_sum16(dot4(uf, p2)), sq2 = sub_sum16(dot4(uf, q2));

  if (sl == 0) {
    float loc = 0.f;
    float xs[3] = {sp0 - sq0, sp1 - sq1, sp2 - sq2};
#pragma unroll
    for (int j = 0; j < 3; j++) {
      float x = xs[j];
      loc += fminf(x, 0.f) - log1pf(expf(-fabsf(x)));
    }
    atomicAdd(acc, loc);
  }
}

// ---------- Frobenius sum-of-squares ----------
__global__ void k_sumsq(const float* __restrict__ x, long n, float* __restrict__ acc) {
  long stride = (long)gridDim.x * blockDim.x;
  float v = 0.f;
  for (long i = (long)blockIdx.x * blockDim.x + threadIdx.x; i < n; i += stride) {
    float t = x[i];
    v = fmaf(t, t, v);
  }
  v = wave_sum(v);
  if ((threadIdx.x & 63) == 0) atomicAdd(acc, v);
}

__global__ void k_final(const float* __restrict__ acc, float* __restrict__ out) {
  out[0] = -acc[0] * (1.0f / (float)BATCH) +
           0.001f * ((sqrtf(acc[1]) + sqrtf(acc[2])) / (float)NI);
}

// ---------- launch ----------
extern "C" void kernel_launch(void* const* d_in, const int* in_sizes, int n_in,
                              void* d_out, int out_size, void* d_ws, size_t ws_size,
                              hipStream_t stream) {
  const float* ue = (const float*)d_in[0];   // (60001, 64)
  const float* ie = (const float*)d_in[1];   // (40001, 64)
  const float* gW = (const float*)d_in[2];   // (2, 64, 64)
  const float* gb = (const float*)d_in[3];   // (2, 64)
  const float* bW = (const float*)d_in[4];   // (3, 2, 64, 64)
  const float* bb = (const float*)d_in[5];   // (3, 2, 64)
  const int* eg = (const int*)d_in[6];       // (2, 1e6)
  const int* eb = (const int*)d_in[7];       // (3, 2, 5e5)
  const int* batch = (const int*)d_in[8];    // (4096, 3, 3)
  float* out = (float*)d_out;

  float* ws = (float*)d_ws;
  const long NE = (long)NN * 64;
  float* G = ws;
  float* B0 = G + NE;
  float* B1 = G + 2 * NE;
  float* B2 = G + 3 * NE;
  float* Bs[3] = {B0, B1, B2};
  float* DINV = G + 4 * NE;             // NN floats
  float* ACC = DINV + NN;               // 3 floats (+pad to 8)
  int* CNT = (int*)(ACC + 8);           // NN ints
  int* OFFS = CNT + NN;                 // NN ints
  int* CURS = OFFS + NN;                // NN ints
  int* PART = CURS + NN;                // 512 ints
  int2* EDGES = (int2*)(PART + 512);    // EG int2 (8 MB)
  unsigned short* TB16 = (unsigned short*)(EDGES + EG);  // NE bf16 (concat, later G)
  unsigned short* AGG16 = TB16 + NE;                     // NE bf16 (h1)

  hipMemsetAsync(ACC, 0, 3 * sizeof(float), stream);

  const long n4 = (long)NN * 16;
  const int CP_B = (int)((n4 + 255) / 256);
  const int MM_B = (NN + 3) / 4;
  const int NB_SCAN = (NN + 511) / 512;  // 196

  auto build_csr = [&](const int* src, const int* dst, int E) {
    hipMemsetAsync(CNT, 0, NN * sizeof(int), stream);
    k_deg_i<<<(E + 255) / 256, 256, 0, stream>>>(dst, E, CNT);
    k_scanA<<<NB_SCAN, 256, 0, stream>>>(CNT, OFFS, PART);
    k_scanB<<<1, 256, 0, stream>>>(PART, NB_SCAN);
    k_scanC<<<(NN + 255) / 256, 256, 0, stream>>>(OFFS, PART, CURS, CNT, DINV);
    k_bucket<<<(E + 255) / 256, 256, 0, stream>>>(src, dst, DINV, E, CURS, EDGES);
  };

  // bf16 concat embedding table
  k_tobf16_concat<<<CP_B, 256, 0, stream>>>((const float4*)ue, (const float4*)ie,
                                            (ushort4*)TB16);

  // ---- global encoder ----
  build_csr(eg, eg + EG, EG);
  k_gcn_l1<<<MM_B, 256, 0, stream>>>(TB16, EDGES, OFFS, CNT, gW, gb, AGG16);
  // res G = concat + h1 + 0.5*h2; also write bf16 shadow of G into TB16
  k_gcn_l2<true, true><<<MM_B, 256, 0, stream>>>(AGG16, EDGES, OFFS, CNT, gW + 4096,
                                                 gb + 64, ue, ie, G, TB16);

  // ---- behavior encoders: gather table = bf16(G) in TB16, base = G ----
  for (int bi = 0; bi < 3; bi++) {
    build_csr(eb + (long)bi * 2 * EB, eb + (long)bi * 2 * EB + EB, EB);
    const float* W = bW + (long)bi * 2 * 4096;
    const float* b = bb + (long)bi * 128;
    k_gcn_l1<<<MM_B, 256, 0, stream>>>(TB16, EDGES, OFFS, CNT, W, b, AGG16);
    k_gcn_l2<false, false><<<MM_B, 256, 0, stream>>>(AGG16, EDGES, OFFS, CNT, W + 4096,
                                                     b + 64, G, nullptr, Bs[bi], nullptr);
  }

  // ---- fused attention + BPR loss ----
  k_loss<<<(BATCH * 3) / 16, 256, 0, stream>>>(G, B0, B1, B2, batch, ACC);

  // ---- regularization norms ----
  k_sumsq<<<512, 256, 0, stream>>>(ue, (long)NU * 64, ACC + 1);
  k_sumsq<<<512, 256, 0, stream>>>(ie, (long)NI * 64, ACC + 2);

  k_final<<<1, 1, 0, stream>>>(ACC, out);
}

// Round 5
// 1090.107 us; speedup vs baseline: 5.0812x; 1.1187x over previous
//
#include <hip/hip_runtime.h>
#include <math.h>

#define NU 60001
#define NI 40001
#define NN 100002   // NU + NI
#define EG 1000000
#define EB 500000
#define BATCH 4096

typedef float floatx2 __attribute__((ext_vector_type(2)));

// ---------- helpers ----------
__device__ inline float wave_sum(float v) {
#pragma unroll
  for (int off = 32; off > 0; off >>= 1) v += __shfl_down(v, off);
  return __shfl(v, 0);
}

__device__ inline float sub_sum16(float v) {  // reduce within 16-lane subgroup
#pragma unroll
  for (int off = 8; off > 0; off >>= 1) v += __shfl_xor(v, off);
  return v;
}

__device__ inline float dot4(float4 a, float4 b) {
  return fmaf(a.x, b.x, fmaf(a.y, b.y, fmaf(a.z, b.z, a.w * b.w)));
}

// fp8 e4m3 (OCP) hardware converts
__device__ inline unsigned char f2fp8(float f) {
  return (unsigned char)(__builtin_amdgcn_cvt_pk_fp8_f32(f, f, 0, false) & 0xff);
}
__device__ inline unsigned int pack4_fp8(float4 v) {
  int pk = __builtin_amdgcn_cvt_pk_fp8_f32(v.x, v.y, 0, false);
  pk = __builtin_amdgcn_cvt_pk_fp8_f32(v.z, v.w, pk, true);
  return (unsigned int)pk;
}

// ---------- fp8 concat table ----------
__global__ void k_tofp8_concat(const float4* __restrict__ ue, const float4* __restrict__ ie,
                               unsigned int* __restrict__ out) {
  long i = (long)blockIdx.x * blockDim.x + threadIdx.x;  // over NN*16 float4s
  if (i >= (long)NN * 16) return;
  float4 v = (i < (long)NU * 16) ? ue[i] : ie[i - (long)NU * 16];
  out[i] = pack4_fp8(v);
}

// ---------- CSR build ----------
__global__ void k_deg_i(const int* __restrict__ dst, int E, int* __restrict__ cnt) {
  int e = blockIdx.x * blockDim.x + threadIdx.x;
  if (e < E) atomicAdd(cnt + dst[e], 1);
}

// exclusive scan of cnt[NN] -> offs[NN]; 512 elems per block
__global__ void k_scanA(const int* __restrict__ cnt, int* __restrict__ offs,
                        int* __restrict__ part) {
  __shared__ int sd[256];
  int t = threadIdx.x;
  int base = blockIdx.x * 512;
  int i0 = base + 2 * t, i1 = i0 + 1;
  int a = (i0 < NN) ? cnt[i0] : 0;
  int b = (i1 < NN) ? cnt[i1] : 0;
  sd[t] = a + b;
  __syncthreads();
  for (int off = 1; off < 256; off <<= 1) {
    int v = (t >= off) ? sd[t - off] : 0;
    __syncthreads();
    sd[t] += v;
    __syncthreads();
  }
  int excl = (t > 0) ? sd[t - 1] : 0;
  if (i0 < NN) offs[i0] = excl;
  if (i1 < NN) offs[i1] = excl + a;
  if (t == 255) part[blockIdx.x] = sd[255];
}

__global__ void k_scanB(int* __restrict__ part, int nb) {
  __shared__ int sd[256];
  int t = threadIdx.x;
  sd[t] = (t < nb) ? part[t] : 0;
  __syncthreads();
  for (int off = 1; off < 256; off <<= 1) {
    int v = (t >= off) ? sd[t - off] : 0;
    __syncthreads();
    sd[t] += v;
    __syncthreads();
  }
  part[t] = (t > 0) ? sd[t - 1] : 0;
}

// finalize offs, init cursor, compute dinv (fused)
__global__ void k_scanC(int* __restrict__ offs, const int* __restrict__ part,
                        int* __restrict__ curs, const int* __restrict__ cnt,
                        float* __restrict__ dinv) {
  int i = blockIdx.x * blockDim.x + threadIdx.x;
  if (i < NN) {
    int v = offs[i] + part[i >> 9];
    offs[i] = v;
    curs[i] = v;
    int c = cnt[i];
    dinv[i] = (c > 0) ? rsqrtf((float)c) : 0.f;
  }
}

// edge payload: x = src byte-offset into fp8 table (src*64), y = coef bits
__global__ void k_bucket(const int* __restrict__ src, const int* __restrict__ dst,
                         const float* __restrict__ dinv, int E, int* __restrict__ curs,
                         int2* __restrict__ edges) {
  int e = blockIdx.x * blockDim.x + threadIdx.x;
  if (e >= E) return;
  int s = src[e], d = dst[e];
  int pos = atomicAdd(curs + d, 1);
  edges[pos] = make_int2(s << 6, __float_as_int(dinv[s] * dinv[d]));
}

// ---------- fused GCN layer core ----------
// Gather: 16-lane subgroups, lane holds 4 dims (fp8 4B load); 4 independent
// row-loads in flight per subgroup iteration (16 edges per wave-iter).
// Then acc -> LDS -> 64x64 matvec (lane=dim) -> +bias -> l2norm.
__device__ inline float gcn_core(const unsigned char* __restrict__ tb,
                                 const int2* __restrict__ edges, int st, int n,
                                 const float (*Ws)[64], float* accs_w,
                                 const float* __restrict__ bias, int lane, int sub, int sl) {
  float4 acc = make_float4(0.f, 0.f, 0.f, 0.f);
  int slo = sl << 2;
  for (int bse = 0; bse < n; bse += 64) {
    int m = min(64, n - bse);
    int2 e = (lane < m) ? edges[st + bse + lane] : make_int2(0, 0);
    int iters = (m + 15) >> 4;
    for (int k = 0; k < iters; k++) {
      int j = (k << 4) + (sub << 2);
      int o0 = __shfl(e.x, j),     c0i = __shfl(e.y, j);
      int o1 = __shfl(e.x, j + 1), c1i = __shfl(e.y, j + 1);
      int o2 = __shfl(e.x, j + 2), c2i = __shfl(e.y, j + 2);
      int o3 = __shfl(e.x, j + 3), c3i = __shfl(e.y, j + 3);
      unsigned int r0 = *(const unsigned int*)(tb + o0 + slo);
      unsigned int r1 = *(const unsigned int*)(tb + o1 + slo);
      unsigned int r2 = *(const unsigned int*)(tb + o2 + slo);
      unsigned int r3 = *(const unsigned int*)(tb + o3 + slo);
      float c0 = __int_as_float(c0i), c1 = __int_as_float(c1i);
      float c2 = __int_as_float(c2i), c3 = __int_as_float(c3i);
      floatx2 l0 = __builtin_amdgcn_cvt_pk_f32_fp8(r0, false);
      floatx2 h0 = __builtin_amdgcn_cvt_pk_f32_fp8(r0, true);
      acc.x = fmaf(l0.x, c0, acc.x); acc.y = fmaf(l0.y, c0, acc.y);
      acc.z = fmaf(h0.x, c0, acc.z); acc.w = fmaf(h0.y, c0, acc.w);
      floatx2 l1 = __builtin_amdgcn_cvt_pk_f32_fp8(r1, false);
      floatx2 h1 = __builtin_amdgcn_cvt_pk_f32_fp8(r1, true);
      acc.x = fmaf(l1.x, c1, acc.x); acc.y = fmaf(l1.y, c1, acc.y);
      acc.z = fmaf(h1.x, c1, acc.z); acc.w = fmaf(h1.y, c1, acc.w);
      floatx2 l2 = __builtin_amdgcn_cvt_pk_f32_fp8(r2, false);
      floatx2 h2 = __builtin_amdgcn_cvt_pk_f32_fp8(r2, true);
      acc.x = fmaf(l2.x, c2, acc.x); acc.y = fmaf(l2.y, c2, acc.y);
      acc.z = fmaf(h2.x, c2, acc.z); acc.w = fmaf(h2.y, c2, acc.w);
      floatx2 l3 = __builtin_amdgcn_cvt_pk_f32_fp8(r3, false);
      floatx2 h3 = __builtin_amdgcn_cvt_pk_f32_fp8(r3, true);
      acc.x = fmaf(l3.x, c3, acc.x); acc.y = fmaf(l3.y, c3, acc.y);
      acc.z = fmaf(h3.x, c3, acc.z); acc.w = fmaf(h3.y, c3, acc.w);
    }
  }
  // reduce across the 4 subgroups
  acc.x += __shfl_xor(acc.x, 16); acc.y += __shfl_xor(acc.y, 16);
  acc.z += __shfl_xor(acc.z, 16); acc.w += __shfl_xor(acc.w, 16);
  acc.x += __shfl_xor(acc.x, 32); acc.y += __shfl_xor(acc.y, 32);
  acc.z += __shfl_xor(acc.z, 32); acc.w += __shfl_xor(acc.w, 32);
  if (sub == 0) *(float4*)(accs_w + slo) = acc;  // wave-local, no barrier needed
  float v0 = bias[lane], v1 = 0.f;
#pragma unroll
  for (int k4 = 0; k4 < 16; k4++) {
    float4 a4 = *(const float4*)(accs_w + (k4 << 2));
    v0 = fmaf(a4.x, Ws[(k4 << 2) + 0][lane], v0);
    v1 = fmaf(a4.y, Ws[(k4 << 2) + 1][lane], v1);
    v0 = fmaf(a4.z, Ws[(k4 << 2) + 2][lane], v0);
    v1 = fmaf(a4.w, Ws[(k4 << 2) + 3][lane], v1);
  }
  float v = v0 + v1;
  float ss = wave_sum(v * v);
  return v / fmaxf(sqrtf(ss), 1e-12f);
}

// Layer 1: h1 = norm(conv(tb)); write fp8 h1 table only.
__global__ void __launch_bounds__(256) k_gcn_l1(
    const unsigned char* __restrict__ tb, const int2* __restrict__ edges,
    const int* __restrict__ offs, const int* __restrict__ cnt,
    const float* __restrict__ W, const float* __restrict__ bias,
    unsigned char* __restrict__ agg8) {
  __shared__ float Ws[64][64];
  __shared__ float accs[4][64];
  int t = threadIdx.x;
  for (int i = t; i < 1024; i += 256) ((float4*)Ws)[i] = ((const float4*)W)[i];
  __syncthreads();
  int w = t >> 6, lane = t & 63, sub = lane >> 4, sl = lane & 15;
  int node = blockIdx.x * 4 + w;
  if (node >= NN) return;
  float h = gcn_core(tb, edges, offs[node], cnt[node], Ws, accs[w], bias, lane, sub, sl);
  agg8[(long)node * 64 + lane] = f2fp8(h);
}

// Layer 2: h2 = norm(conv(h1_8)); res = base + h1 + 0.5*h2 (+ optional fp8 shadow).
template <bool BASE_CONCAT, bool WRITE_FP8>
__global__ void __launch_bounds__(256) k_gcn_l2(
    const unsigned char* __restrict__ h1_8, const int2* __restrict__ edges,
    const int* __restrict__ offs, const int* __restrict__ cnt,
    const float* __restrict__ W, const float* __restrict__ bias,
    const float* __restrict__ base, const float* __restrict__ base2,
    float* __restrict__ res, unsigned char* __restrict__ res8) {
  __shared__ float Ws[64][64];
  __shared__ float accs[4][64];
  int t = threadIdx.x;
  for (int i = t; i < 1024; i += 256) ((float4*)Ws)[i] = ((const float4*)W)[i];
  __syncthreads();
  int w = t >> 6, lane = t & 63, sub = lane >> 4, sl = lane & 15;
  int node = blockIdx.x * 4 + w;
  if (node >= NN) return;
  float h = gcn_core(h1_8, edges, offs[node], cnt[node], Ws, accs[w], bias, lane, sub, sl);
  long idx = (long)node * 64 + lane;
  float own = __builtin_amdgcn_cvt_f32_fp8((unsigned int)h1_8[idx], 0);
  float b0;
  if (BASE_CONCAT) b0 = (node < NU) ? base[idx] : base2[(long)(node - NU) * 64 + lane];
  else b0 = base[idx];
  float r = b0 + own + 0.5f * h;
  res[idx] = r;
  if (WRITE_FP8) res8[idx] = f2fp8(r);
}

// ---------- fused attention + BPR loss (16-lane subgroups, float4/lane) ----------
__device__ inline void item_iw4(const float* __restrict__ G, const float* __restrict__ B0,
                                const float* __restrict__ B1, const float* __restrict__ B2,
                                long o, float4& iw0, float4& iw1, float4& iw2) {
  float4 g = *(const float4*)(G + o);
  float4 t0 = *(const float4*)(B0 + o);
  float4 t1 = *(const float4*)(B1 + o);
  float4 t2 = *(const float4*)(B2 + o);
  float g00 = sub_sum16(dot4(t0, t0)), g01 = sub_sum16(dot4(t0, t1));
  float g02 = sub_sum16(dot4(t0, t2)), g11 = sub_sum16(dot4(t1, t1));
  float g12 = sub_sum16(dot4(t1, t2)), g22 = sub_sum16(dot4(t2, t2));
  const float S = 0.125f;
  float gm[3][3] = {{g00, g01, g02}, {g01, g11, g12}, {g02, g12, g22}};
  float4* out[3] = {&iw0, &iw1, &iw2};
#pragma unroll
  for (int j = 0; j < 3; j++) {
    float a0 = gm[j][0] * S, a1 = gm[j][1] * S, a2 = gm[j][2] * S;
    float m = fmaxf(a0, fmaxf(a1, a2));
    float e0 = expf(a0 - m), e1 = expf(a1 - m), e2 = expf(a2 - m);
    float inv = 1.f / (e0 + e1 + e2);
    float w0 = e0 * inv, w1 = e1 * inv, w2 = e2 * inv;
    float4 r;
    r.x = fmaf(0.55f, w0 * t0.x + w1 * t1.x + w2 * t2.x, g.x);
    r.y = fmaf(0.55f, w0 * t0.y + w1 * t1.y + w2 * t2.y, g.y);
    r.z = fmaf(0.55f, w0 * t0.z + w1 * t1.z + w2 * t2.z, g.z);
    r.w = fmaf(0.55f, w0 * t0.w + w1 * t1.w + w2 * t2.w, g.w);
    *out[j] = r;
  }
}

__global__ void __launch_bounds__(256) k_loss(
    const float* __restrict__ G, const float* __restrict__ B0,
    const float* __restrict__ B1, const float* __restrict__ B2,
    const int* __restrict__ batch, float* __restrict__ acc) {
  int tid = blockIdx.x * blockDim.x + threadIdx.x;
  int lane = tid & 63;
  int sub = lane >> 4, sl = lane & 15;
  int task = (tid >> 6) * 4 + sub;  // task = k*3 + i
  if (task >= BATCH * 3) return;
  int i = task % 3;
  const int* bd = batch + (long)task * 3;
  int u = bd[0], p = bd[1], q = bd[2];

  float4 uf;
  {
    long o = (long)u * 64 + sl * 4;
    float4 g = *(const float4*)(G + o);
    float4 t0 = *(const float4*)(B0 + o);
    float4 t1 = *(const float4*)(B1 + o);
    float4 t2 = *(const float4*)(B2 + o);
    float4 ti = (i == 0) ? t0 : ((i == 1) ? t1 : t2);
    float a0 = sub_sum16(dot4(ti, t0)) * 0.125f;
    float a1 = sub_sum16(dot4(ti, t1)) * 0.125f;
    float a2 = sub_sum16(dot4(ti, t2)) * 0.125f;
    float m = fmaxf(a0, fmaxf(a1, a2));
    float e0 = expf(a0 - m), e1 = expf(a1 - m), e2 = expf(a2 - m);
    float inv = 1.f / (e0 + e1 + e2);
    float w0 = e0 * inv, w1 = e1 * inv, w2 = e2 * inv;
    uf.x = fmaf(2.35f, g.x, 0.242f * (w0 * t0.x + w1 * t1.x + w2 * t2.x));
    uf.y = fmaf(2.35f, g.y, 0.242f * (w0 * t0.y + w1 * t1.y + w2 * t2.y));
    uf.z = fmaf(2.35f, g.z, 0.242f * (w0 * t0.z + w1 * t1.z + w2 * t2.z));
    uf.w = fmaf(2.35f, g.w, 0.242f * (w0 * t0.w + w1 * t1.w + w2 * t2.w));
  }

  float4 p0, p1, p2, q0, q1, q2;
  item_iw4(G, B0, B1, B2, ((long)(NU + p)) * 64 + sl * 4, p0, p1, p2);
  item_iw4(G, B0, B1, B2, ((long)(NU + q)) * 64 + sl * 4, q0, q1, q2);

  float sp0 = sub_sum16(dot4(uf, p0)), sq0 = sub_sum16(dot4(uf, q0));
  float sp1 = sub_sum16(dot4(uf, p1)), sq1 = sub_sum16(dot4(uf, q1));
  float sp2 = sub_sum16(dot4(uf, p2)), sq2 = sub_sum16(dot4(uf, q2));

  if (sl == 0) {
    float loc = 0.f;
    float xs[3] = {sp0 - sq0, sp1 - sq1, sp2 - sq2};
#pragma unroll
    for (int j = 0; j < 3; j++) {
      float x = xs[j];
      loc += fminf(x, 0.f) - log1pf(expf(-fabsf(x)));
    }
    atomicAdd(acc, loc);
  }
}

// ---------- Frobenius sum-of-squares ----------
__global__ void k_sumsq(const float* __restrict__ x, long n, float* __restrict__ acc) {
  long stride = (long)gridDim.x * blockDim.x;
  float v = 0.f;
  for (long i = (long)blockIdx.x * blockDim.x + threadIdx.x; i < n; i += stride) {
    float t = x[i];
    v = fmaf(t, t, v);
  }
  v = wave_sum(v);
  if ((threadIdx.x & 63) == 0) atomicAdd(acc, v);
}

__global__ void k_final(const float* __restrict__ acc, float* __restrict__ out) {
  out[0] = -acc[0] * (1.0f / (float)BATCH) +
           0.001f * ((sqrtf(acc[1]) + sqrtf(acc[2])) / (float)NI);
}

// ---------- launch ----------
extern "C" void kernel_launch(void* const* d_in, const int* in_sizes, int n_in,
                              void* d_out, int out_size, void* d_ws, size_t ws_size,
                              hipStream_t stream) {
  const float* ue = (const float*)d_in[0];   // (60001, 64)
  const float* ie = (const float*)d_in[1];   // (40001, 64)
  const float* gW = (const float*)d_in[2];   // (2, 64, 64)
  const float* gb = (const float*)d_in[3];   // (2, 64)
  const float* bW = (const float*)d_in[4];   // (3, 2, 64, 64)
  const float* bb = (const float*)d_in[5];   // (3, 2, 64)
  const int* eg = (const int*)d_in[6];       // (2, 1e6)
  const int* eb = (const int*)d_in[7];       // (3, 2, 5e5)
  const int* batch = (const int*)d_in[8];    // (4096, 3, 3)
  float* out = (float*)d_out;

  float* ws = (float*)d_ws;
  const long NE = (long)NN * 64;
  float* G = ws;
  float* B0 = G + NE;
  float* B1 = G + 2 * NE;
  float* B2 = G + 3 * NE;
  float* Bs[3] = {B0, B1, B2};
  float* DINV = G + 4 * NE;             // NN floats
  float* ACC = DINV + NN;               // 3 floats (+pad to 8)
  int* CNT = (int*)(ACC + 8);           // NN ints
  int* OFFS = CNT + NN;                 // NN ints
  int* CURS = OFFS + NN;                // NN ints
  int* PART = CURS + NN;                // 512 ints
  int2* EDGES = (int2*)(PART + 512);    // EG int2 (8 MB)
  unsigned char* TB8 = (unsigned char*)(EDGES + EG);  // NE fp8 (concat, later G)
  unsigned char* AGG8 = TB8 + NE;                     // NE fp8 (h1)

  hipMemsetAsync(ACC, 0, 3 * sizeof(float), stream);

  const long n4 = (long)NN * 16;
  const int CP_B = (int)((n4 + 255) / 256);
  const int MM_B = (NN + 3) / 4;
  const int NB_SCAN = (NN + 511) / 512;  // 196

  auto build_csr = [&](const int* src, const int* dst, int E) {
    hipMemsetAsync(CNT, 0, NN * sizeof(int), stream);
    k_deg_i<<<(E + 255) / 256, 256, 0, stream>>>(dst, E, CNT);
    k_scanA<<<NB_SCAN, 256, 0, stream>>>(CNT, OFFS, PART);
    k_scanB<<<1, 256, 0, stream>>>(PART, NB_SCAN);
    k_scanC<<<(NN + 255) / 256, 256, 0, stream>>>(OFFS, PART, CURS, CNT, DINV);
    k_bucket<<<(E + 255) / 256, 256, 0, stream>>>(src, dst, DINV, E, CURS, EDGES);
  };

  // fp8 concat embedding table
  k_tofp8_concat<<<CP_B, 256, 0, stream>>>((const float4*)ue, (const float4*)ie,
                                           (unsigned int*)TB8);

  // ---- global encoder ----
  build_csr(eg, eg + EG, EG);
  k_gcn_l1<<<MM_B, 256, 0, stream>>>(TB8, EDGES, OFFS, CNT, gW, gb, AGG8);
  // res G = concat + h1 + 0.5*h2; also write fp8 shadow of G into TB8
  k_gcn_l2<true, true><<<MM_B, 256, 0, stream>>>(AGG8, EDGES, OFFS, CNT, gW + 4096,
                                                 gb + 64, ue, ie, G, TB8);

  // ---- behavior encoders: gather table = fp8(G) in TB8, base = G ----
  for (int bi = 0; bi < 3; bi++) {
    build_csr(eb + (long)bi * 2 * EB, eb + (long)bi * 2 * EB + EB, EB);
    const float* W = bW + (long)bi * 2 * 4096;
    const float* b = bb + (long)bi * 128;
    k_gcn_l1<<<MM_B, 256, 0, stream>>>(TB8, EDGES, OFFS, CNT, W, b, AGG8);
    k_gcn_l2<false, false><<<MM_B, 256, 0, stream>>>(AGG8, EDGES, OFFS, CNT, W + 4096,
                                                     b + 64, G, nullptr, Bs[bi], nullptr);
  }

  // ---- fused attention + BPR loss ----
  k_loss<<<(BATCH * 3) / 16, 256, 0, stream>>>(G, B0, B1, B2, batch, ACC);

  // ---- regularization norms ----
  k_sumsq<<<512, 256, 0, stream>>>(ue, (long)NU * 64, ACC + 1);
  k_sumsq<<<512, 256, 0, stream>>>(ie, (long)NI * 64, ACC + 2);

  k_final<<<1, 1, 0, stream>>>(ACC, out);
}

// Round 6
// 694.605 us; speedup vs baseline: 7.9744x; 1.5694x over previous
//
#include <hip/hip_runtime.h>
#include <math.h>

#define NU 60001
#define NI 40001
#define NN 100002   // NU + NI
#define EG 1000000
#define EB 500000
#define BATCH 4096

typedef float floatx2 __attribute__((ext_vector_type(2)));
typedef short bf16x8 __attribute__((ext_vector_type(8)));
typedef float f32x4 __attribute__((ext_vector_type(4)));

// ---------- helpers ----------
__device__ inline float wave_sum(float v) {
#pragma unroll
  for (int off = 32; off > 0; off >>= 1) v += __shfl_down(v, off);
  return __shfl(v, 0);
}

__device__ inline float sub_sum16(float v) {  // reduce within 16-lane subgroup
#pragma unroll
  for (int off = 8; off > 0; off >>= 1) v += __shfl_xor(v, off);
  return v;
}

__device__ inline float dot4(float4 a, float4 b) {
  return fmaf(a.x, b.x, fmaf(a.y, b.y, fmaf(a.z, b.z, a.w * b.w)));
}

__device__ inline unsigned short f2b(float f) {  // fp32 -> bf16 RNE
  unsigned u = __float_as_uint(f);
  return (unsigned short)((u + 0x7fffu + ((u >> 16) & 1u)) >> 16);
}

// fp8 e4m3 (OCP) hardware converts
__device__ inline unsigned char f2fp8(float f) {
  return (unsigned char)(__builtin_amdgcn_cvt_pk_fp8_f32(f, f, 0, false) & 0xff);
}
__device__ inline unsigned int pack4_fp8(float4 v) {
  int pk = __builtin_amdgcn_cvt_pk_fp8_f32(v.x, v.y, 0, false);
  pk = __builtin_amdgcn_cvt_pk_fp8_f32(v.z, v.w, pk, true);
  return (unsigned int)pk;
}

// ---------- fp8 concat table ----------
__global__ void k_tofp8_concat(const float4* __restrict__ ue, const float4* __restrict__ ie,
                               unsigned int* __restrict__ out) {
  long i = (long)blockIdx.x * blockDim.x + threadIdx.x;  // over NN*16 float4s
  if (i >= (long)NN * 16) return;
  float4 v = (i < (long)NU * 16) ? ue[i] : ie[i - (long)NU * 16];
  out[i] = pack4_fp8(v);
}

// ---------- CSR build (batched over gridDim.y sets) ----------
__global__ void k_deg(const int* __restrict__ eb, int Eper, int* __restrict__ cnt3) {
  int e = blockIdx.x * blockDim.x + threadIdx.x;
  int set = blockIdx.y;
  if (e < Eper) atomicAdd(cnt3 + set * NN + eb[(long)set * 2 * Eper + Eper + e], 1);
}

__global__ void k_scanA(const int* __restrict__ cnt, int* __restrict__ offs,
                        int* __restrict__ part) {
  __shared__ int sd[256];
  int t = threadIdx.x, set = blockIdx.y;
  int base = set * NN;
  int i0 = blockIdx.x * 512 + 2 * t, i1 = i0 + 1;
  int a = (i0 < NN) ? cnt[base + i0] : 0;
  int b = (i1 < NN) ? cnt[base + i1] : 0;
  sd[t] = a + b;
  __syncthreads();
  for (int off = 1; off < 256; off <<= 1) {
    int v = (t >= off) ? sd[t - off] : 0;
    __syncthreads();
    sd[t] += v;
    __syncthreads();
  }
  int excl = (t > 0) ? sd[t - 1] : 0;
  if (i0 < NN) offs[base + i0] = excl;
  if (i1 < NN) offs[base + i1] = excl + a;
  if (t == 255) part[set * 256 + blockIdx.x] = sd[255];
}

__global__ void k_scanB(int* __restrict__ part) {
  __shared__ int sd[256];
  int t = threadIdx.x, set = blockIdx.x;
  sd[t] = (t < 196) ? part[set * 256 + t] : 0;
  __syncthreads();
  for (int off = 1; off < 256; off <<= 1) {
    int v = (t >= off) ? sd[t - off] : 0;
    __syncthreads();
    sd[t] += v;
    __syncthreads();
  }
  part[set * 256 + t] = (t > 0) ? sd[t - 1] : 0;
}

__global__ void k_scanC(int* __restrict__ offs, const int* __restrict__ part,
                        int* __restrict__ curs, const int* __restrict__ cnt,
                        float* __restrict__ dinv) {
  int i = blockIdx.x * blockDim.x + threadIdx.x;
  int set = blockIdx.y;
  if (i < NN) {
    int gi = set * NN + i;
    int v = offs[gi] + part[set * 256 + (i >> 9)];
    offs[gi] = v;
    curs[gi] = v;
    int c = cnt[gi];
    dinv[gi] = (c > 0) ? rsqrtf((float)c) : 0.f;
  }
}

// edge payload: x = src byte-offset into fp8 table (src*64), y = coef bits
__global__ void k_bucket(const int* __restrict__ eb, int Eper,
                         const float* __restrict__ dinv, int* __restrict__ curs,
                         int2* __restrict__ edges) {
  int e = blockIdx.x * blockDim.x + threadIdx.x;
  int set = blockIdx.y;
  if (e >= Eper) return;
  const int* sp = eb + (long)set * 2 * Eper;
  int s = sp[e], d = sp[Eper + e];
  int pos = atomicAdd(curs + set * NN + d, 1);
  edges[(long)set * Eper + pos] =
      make_int2(s << 6, __float_as_int(dinv[set * NN + s] * dinv[set * NN + d]));
}

// ---------- fused GCN layer: gather -> MFMA matvec -> bias -> l2norm -> out ----------
// 16 nodes per block (256 threads = 4 waves). Gather: one node per 16-lane
// subgroup (4 nodes/wave), 4 row-loads in flight/lane. acc -> LDS bf16
// (padded stride 72 shorts). MFMA: wave w computes 16 nodes x dims[16w..16w+16)
// via 2x mfma_f32_16x16x32_bf16 with W held in registers (B-frags).
// MODE 0: global l1  (tb=TB8,  out8=AGG8)
// MODE 1: global l2  (tb=AGG8, base=ue/ie, res=G, out8=TB8 shadow)
// MODE 2: behavior l1 (tb=TB8, out8=AGG8+set*NE), set = blockIdx.y
// MODE 3: behavior l2 (tb=AGG8+set*NE, base=G, res=B0+set*NE)
template <int MODE>
__global__ void __launch_bounds__(256) k_gcn(
    const unsigned char* __restrict__ tb, const int2* __restrict__ edges,
    const int* __restrict__ offs, const int* __restrict__ cnt,
    const float* __restrict__ Wb, const float* __restrict__ biasb,
    const float* __restrict__ base, const float* __restrict__ base2,
    float* __restrict__ res, unsigned char* __restrict__ out8) {
  __shared__ __align__(16) short accs[16][72];  // bf16 acc, stride 144B (2-way banks)
  __shared__ float ssq[16][4];
  const long NE = (long)NN * 64;

  int t = threadIdx.x;
  int w = t >> 6, lane = t & 63;
  int sub = lane >> 4, sl = lane & 15;
  int set = blockIdx.y;

  const float *W, *bias;
  if (MODE <= 1) { W = Wb; bias = biasb; }
  else {
    W = Wb + (long)set * 8192 + (MODE == 3 ? 4096 : 0);
    bias = biasb + set * 128 + (MODE == 3 ? 64 : 0);
  }
  const unsigned char* tbl = (MODE == 3) ? tb + set * NE : tb;
  const int2* edg = (MODE >= 2) ? edges + (long)set * EB : edges;
  const int* offp = offs + set * NN;
  const int* cntp = cnt + set * NN;

  // ---- B-frags: W columns in registers, bf16 ----
  int ncol = (w << 4) + sl;  // output dim for this lane
  bf16x8 bf0, bf1;
#pragma unroll
  for (int j = 0; j < 8; j++) {
    bf0[j] = (short)f2b(W[(sub * 8 + j) * 64 + ncol]);
    bf1[j] = (short)f2b(W[(32 + sub * 8 + j) * 64 + ncol]);
  }
  float bias_n = bias[ncol];

  // ---- gather: node per subgroup ----
  int nb0 = blockIdx.x * 16;
  int node = nb0 + (w << 2) + sub;
  float4 acc = make_float4(0.f, 0.f, 0.f, 0.f);
  int st = 0, deg = 0;
  if (node < NN) { st = offp[node]; deg = cntp[node]; }
  int mx = deg;
  mx = max(mx, __shfl_xor(mx, 16));
  mx = max(mx, __shfl_xor(mx, 32));
  int lbase = lane & 48;  // sub*16
  for (int ch = 0; ch < mx; ch += 16) {
    int rem = deg - ch;
    int2 e = (sl < rem) ? edg[st + ch + sl] : make_int2(0, 0);
#pragma unroll
    for (int i = 0; i < 16; i += 4) {
      int j0 = lbase + i;
      int o0 = __shfl(e.x, j0),     c0i = __shfl(e.y, j0);
      int o1 = __shfl(e.x, j0 + 1), c1i = __shfl(e.y, j0 + 1);
      int o2 = __shfl(e.x, j0 + 2), c2i = __shfl(e.y, j0 + 2);
      int o3 = __shfl(e.x, j0 + 3), c3i = __shfl(e.y, j0 + 3);
      unsigned r0 = *(const unsigned*)(tbl + o0 + (sl << 2));
      unsigned r1 = *(const unsigned*)(tbl + o1 + (sl << 2));
      unsigned r2 = *(const unsigned*)(tbl + o2 + (sl << 2));
      unsigned r3 = *(const unsigned*)(tbl + o3 + (sl << 2));
      float c0 = __int_as_float(c0i), c1 = __int_as_float(c1i);
      float c2 = __int_as_float(c2i), c3 = __int_as_float(c3i);
      floatx2 l0 = __builtin_amdgcn_cvt_pk_f32_fp8(r0, false);
      floatx2 h0 = __builtin_amdgcn_cvt_pk_f32_fp8(r0, true);
      acc.x = fmaf(l0.x, c0, acc.x); acc.y = fmaf(l0.y, c0, acc.y);
      acc.z = fmaf(h0.x, c0, acc.z); acc.w = fmaf(h0.y, c0, acc.w);
      floatx2 l1 = __builtin_amdgcn_cvt_pk_f32_fp8(r1, false);
      floatx2 h1 = __builtin_amdgcn_cvt_pk_f32_fp8(r1, true);
      acc.x = fmaf(l1.x, c1, acc.x); acc.y = fmaf(l1.y, c1, acc.y);
      acc.z = fmaf(h1.x, c1, acc.z); acc.w = fmaf(h1.y, c1, acc.w);
      floatx2 l2 = __builtin_amdgcn_cvt_pk_f32_fp8(r2, false);
      floatx2 h2 = __builtin_amdgcn_cvt_pk_f32_fp8(r2, true);
      acc.x = fmaf(l2.x, c2, acc.x); acc.y = fmaf(l2.y, c2, acc.y);
      acc.z = fmaf(h2.x, c2, acc.z); acc.w = fmaf(h2.y, c2, acc.w);
      floatx2 l3 = __builtin_amdgcn_cvt_pk_f32_fp8(r3, false);
      floatx2 h3 = __builtin_amdgcn_cvt_pk_f32_fp8(r3, true);
      acc.x = fmaf(l3.x, c3, acc.x); acc.y = fmaf(l3.y, c3, acc.y);
      acc.z = fmaf(h3.x, c3, acc.z); acc.w = fmaf(h3.y, c3, acc.w);
    }
  }
  // pack acc -> bf16 LDS row (local node = 4w+sub; lane covers dims 4sl..4sl+3)
  short4 pk;
  pk.x = (short)f2b(acc.x); pk.y = (short)f2b(acc.y);
  pk.z = (short)f2b(acc.z); pk.w = (short)f2b(acc.w);
  *(short4*)&accs[(w << 2) + sub][sl << 2] = pk;
  __syncthreads();

  // ---- MFMA: A[m=sl][k=sub*8+j] from LDS; D col=lane&15, row=sub*4+reg ----
  bf16x8 a0 = *(const bf16x8*)&accs[sl][sub << 3];
  bf16x8 a1 = *(const bf16x8*)&accs[sl][32 + (sub << 3)];
  f32x4 c4 = {0.f, 0.f, 0.f, 0.f};
  c4 = __builtin_amdgcn_mfma_f32_16x16x32_bf16(a0, bf0, c4, 0, 0, 0);
  c4 = __builtin_amdgcn_mfma_f32_16x16x32_bf16(a1, bf1, c4, 0, 0, 0);

  float v[4];
#pragma unroll
  for (int r = 0; r < 4; r++) v[r] = c4[r] + bias_n;
  // per-node sum of squares: partial over this wave's 16 dims
#pragma unroll
  for (int r = 0; r < 4; r++) {
    float p = sub_sum16(v[r] * v[r]);
    if (sl == 0) ssq[(sub << 2) + r][w] = p;
  }
  __syncthreads();
#pragma unroll
  for (int r = 0; r < 4; r++) {
    int ml = (sub << 2) + r;  // local node (= D row)
    float4 s4 = *(const float4*)ssq[ml];
    float ss = s4.x + s4.y + s4.z + s4.w;
    float nrm = fmaxf(sqrtf(ss), 1e-12f);
    float h = v[r] / nrm;
    int gm = nb0 + ml;
    if (gm < NN) {
      long idx = (long)gm * 64 + ncol;
      if (MODE == 0) {
        out8[idx] = f2fp8(h);
      } else if (MODE == 2) {
        out8[set * NE + idx] = f2fp8(h);
      } else if (MODE == 1) {
        float own = __builtin_amdgcn_cvt_f32_fp8((unsigned int)tbl[idx], 0);
        float b0 = (gm < NU) ? base[idx] : base2[(long)(gm - NU) * 64 + ncol];
        float rr = b0 + own + 0.5f * h;
        res[idx] = rr;
        out8[idx] = f2fp8(rr);
      } else {  // MODE 3
        float own = __builtin_amdgcn_cvt_f32_fp8((unsigned int)tbl[idx], 0);
        float rr = base[idx] + own + 0.5f * h;
        (res + set * NE)[idx] = rr;
      }
    }
  }
}

// ---------- fused attention + BPR loss (16-lane subgroups, float4/lane) ----------
__device__ inline void item_iw4(const float* __restrict__ G, const float* __restrict__ B0,
                                const float* __restrict__ B1, const float* __restrict__ B2,
                                long o, float4& iw0, float4& iw1, float4& iw2) {
  float4 g = *(const float4*)(G + o);
  float4 t0 = *(const float4*)(B0 + o);
  float4 t1 = *(const float4*)(B1 + o);
  float4 t2 = *(const float4*)(B2 + o);
  float g00 = sub_sum16(dot4(t0, t0)), g01 = sub_sum16(dot4(t0, t1));
  float g02 = sub_sum16(dot4(t0, t2)), g11 = sub_sum16(dot4(t1, t1));
  float g12 = sub_sum16(dot4(t1, t2)), g22 = sub_sum16(dot4(t2, t2));
  const float S = 0.125f;
  float gm[3][3] = {{g00, g01, g02}, {g01, g11, g12}, {g02, g12, g22}};
  float4* out[3] = {&iw0, &iw1, &iw2};
#pragma unroll
  for (int j = 0; j < 3; j++) {
    float a0 = gm[j][0] * S, a1 = gm[j][1] * S, a2 = gm[j][2] * S;
    float m = fmaxf(a0, fmaxf(a1, a2));
    float e0 = expf(a0 - m), e1 = expf(a1 - m), e2 = expf(a2 - m);
    float inv = 1.f / (e0 + e1 + e2);
    float w0 = e0 * inv, w1 = e1 * inv, w2 = e2 * inv;
    float4 r;
    r.x = fmaf(0.55f, w0 * t0.x + w1 * t1.x + w2 * t2.x, g.x);
    r.y = fmaf(0.55f, w0 * t0.y + w1 * t1.y + w2 * t2.y, g.y);
    r.z = fmaf(0.55f, w0 * t0.z + w1 * t1.z + w2 * t2.z, g.z);
    r.w = fmaf(0.55f, w0 * t0.w + w1 * t1.w + w2 * t2.w, g.w);
    *out[j] = r;
  }
}

__global__ void __launch_bounds__(256) k_loss(
    const float* __restrict__ G, const float* __restrict__ B0,
    const float* __restrict__ B1, const float* __restrict__ B2,
    const int* __restrict__ batch, float* __restrict__ acc) {
  int tid = blockIdx.x * blockDim.x + threadIdx.x;
  int lane = tid & 63;
  int sub = lane >> 4, sl = lane & 15;
  int task = (tid >> 6) * 4 + sub;  // task = k*3 + i
  if (task >= BATCH * 3) return;
  int i = task % 3;
  const int* bd = batch + (long)task * 3;
  int u = bd[0], p = bd[1], q = bd[2];

  float4 uf;
  {
    long o = (long)u * 64 + sl * 4;
    float4 g = *(const float4*)(G + o);
    float4 t0 = *(const float4*)(B0 + o);
    float4 t1 = *(const float4*)(B1 + o);
    float4 t2 = *(const float4*)(B2 + o);
    float4 ti = (i == 0) ? t0 : ((i == 1) ? t1 : t2);
    float a0 = sub_sum16(dot4(ti, t0)) * 0.125f;
    float a1 = sub_sum16(dot4(ti, t1)) * 0.125f;
    float a2 = sub_sum16(dot4(ti, t2)) * 0.125f;
    float m = fmaxf(a0, fmaxf(a1, a2));
    float e0 = expf(a0 - m), e1 = expf(a1 - m), e2 = expf(a2 - m);
    float inv = 1.f / (e0 + e1 + e2);
    float w0 = e0 * inv, w1 = e1 * inv, w2 = e2 * inv;
    uf.x = fmaf(2.35f, g.x, 0.242f * (w0 * t0.x + w1 * t1.x + w2 * t2.x));
    uf.y = fmaf(2.35f, g.y, 0.242f * (w0 * t0.y + w1 * t1.y + w2 * t2.y));
    uf.z = fmaf(2.35f, g.z, 0.242f * (w0 * t0.z + w1 * t1.z + w2 * t2.z));
    uf.w = fmaf(2.35f, g.w, 0.242f * (w0 * t0.w + w1 * t1.w + w2 * t2.w));
  }

  float4 p0, p1, p2, q0, q1, q2;
  item_iw4(G, B0, B1, B2, ((long)(NU + p)) * 64 + sl * 4, p0, p1, p2);
  item_iw4(G, B0, B1, B2, ((long)(NU + q)) * 64 + sl * 4, q0, q1, q2);

  float sp0 = sub_sum16(dot4(uf, p0)), sq0 = sub_sum16(dot4(uf, q0));
  float sp1 = sub_sum16(dot4(uf, p1)), sq1 = sub_sum16(dot4(uf, q1));
  float sp2 = sub_sum16(dot4(uf, p2)), sq2 = sub_sum16(dot4(uf, q2));

  if (sl == 0) {
    float loc = 0.f;
    float xs[3] = {sp0 - sq0, sp1 - sq1, sp2 - sq2};
#pragma unroll
    for (int j = 0; j < 3; j++) {
      float x = xs[j];
      loc += fminf(x, 0.f) - log1pf(expf(-fabsf(x)));
    }
    atomicAdd(acc, loc);
  }
}

// ---------- Frobenius sum-of-squares ----------
__global__ void k_sumsq(const float* __restrict__ x, long n, float* __restrict__ acc) {
  long stride = (long)gridDim.x * blockDim.x;
  float v = 0.f;
  for (long i = (long)blockIdx.x * blockDim.x + threadIdx.x; i < n; i += stride) {
    float t = x[i];
    v = fmaf(t, t, v);
  }
  v = wave_sum(v);
  if ((threadIdx.x & 63) == 0) atomicAdd(acc, v);
}

__global__ void k_final(const float* __restrict__ acc, float* __restrict__ out) {
  out[0] = -acc[0] * (1.0f / (float)BATCH) +
           0.001f * ((sqrtf(acc[1]) + sqrtf(acc[2])) / (float)NI);
}

// ---------- launch ----------
extern "C" void kernel_launch(void* const* d_in, const int* in_sizes, int n_in,
                              void* d_out, int out_size, void* d_ws, size_t ws_size,
                              hipStream_t stream) {
  const float* ue = (const float*)d_in[0];   // (60001, 64)
  const float* ie = (const float*)d_in[1];   // (40001, 64)
  const float* gW = (const float*)d_in[2];   // (2, 64, 64)
  const float* gb = (const float*)d_in[3];   // (2, 64)
  const float* bW = (const float*)d_in[4];   // (3, 2, 64, 64)
  const float* bb = (const float*)d_in[5];   // (3, 2, 64)
  const int* eg = (const int*)d_in[6];       // (2, 1e6)
  const int* eb = (const int*)d_in[7];       // (3, 2, 5e5)
  const int* batch = (const int*)d_in[8];    // (4096, 3, 3)
  float* out = (float*)d_out;

  float* ws = (float*)d_ws;
  const long NE = (long)NN * 64;
  float* G = ws;
  float* B0 = G + NE;                        // B0,B1,B2 contiguous
  float* DINV = G + 4 * NE;                  // 3*NN
  float* ACC = DINV + 3 * NN;                // 8 floats
  int* CNT = (int*)(ACC + 8);                // 3*NN
  int* OFFS = CNT + 3 * NN;                  // 3*NN
  int* CURS = OFFS + 3 * NN;                 // 3*NN
  int* PART = CURS + 3 * NN;                 // 3*256
  int2* EDGES = (int2*)(PART + 1024);        // max(EG, 3*EB) = 1.5M int2
  unsigned char* TB8 = (unsigned char*)(EDGES + 3 * EB);  // NE bytes
  unsigned char* AGG8 = TB8 + NE;                         // 3*NE bytes

  hipMemsetAsync(ACC, 0, 3 * sizeof(float), stream);

  const long n4 = (long)NN * 16;
  const int CP_B = (int)((n4 + 255) / 256);
  const int GB = (NN + 15) / 16;  // 6251 node-blocks

  auto build_csr = [&](const int* ebase, int Eper, int nsets) {
    hipMemsetAsync(CNT, 0, nsets * NN * sizeof(int), stream);
    dim3 ge((Eper + 255) / 256, nsets);
    dim3 gn((NN + 255) / 256, nsets);
    dim3 gs(196, nsets);
    k_deg<<<ge, 256, 0, stream>>>(ebase, Eper, CNT);
    k_scanA<<<gs, 256, 0, stream>>>(CNT, OFFS, PART);
    k_scanB<<<nsets, 256, 0, stream>>>(PART);
    k_scanC<<<gn, 256, 0, stream>>>(OFFS, PART, CURS, CNT, DINV);
    k_bucket<<<ge, 256, 0, stream>>>(ebase, Eper, DINV, CURS, EDGES);
  };

  // fp8 concat embedding table
  k_tofp8_concat<<<CP_B, 256, 0, stream>>>((const float4*)ue, (const float4*)ie,
                                           (unsigned int*)TB8);

  // ---- global encoder ----
  build_csr(eg, EG, 1);
  k_gcn<0><<<dim3(GB, 1), 256, 0, stream>>>(TB8, EDGES, OFFS, CNT, gW, gb,
                                            nullptr, nullptr, nullptr, AGG8);
  k_gcn<1><<<dim3(GB, 1), 256, 0, stream>>>(AGG8, EDGES, OFFS, CNT, gW + 4096, gb + 64,
                                            ue, ie, G, TB8);

  // ---- behavior encoders (batched over 3 sets) ----
  build_csr(eb, EB, 3);
  k_gcn<2><<<dim3(GB, 3), 256, 0, stream>>>(TB8, EDGES, OFFS, CNT, bW, bb,
                                            nullptr, nullptr, nullptr, AGG8);
  k_gcn<3><<<dim3(GB, 3), 256, 0, stream>>>(AGG8, EDGES, OFFS, CNT, bW, bb,
                                            G, nullptr, B0, nullptr);

  // ---- fused attention + BPR loss ----
  k_loss<<<(BATCH * 3) / 16, 256, 0, stream>>>(G, B0, B0 + NE, B0 + 2 * NE, batch, ACC);

  // ---- regularization norms ----
  k_sumsq<<<512, 256, 0, stream>>>(ue, (long)NU * 64, ACC + 1);
  k_sumsq<<<512, 256, 0, stream>>>(ie, (long)NI * 64, ACC + 2);

  k_final<<<1, 1, 0, stream>>>(ACC, out);
}